// Round 9
// baseline (133.781 us; speedup 1.0000x reference)
//
#include <hip/hip_runtime.h>

#define DIMS 1024
#define DEXT 1088        // DIMS + 64: one extra K-tile carrying [h,l,1,1] norm digits
#define KNN_K 8
#define BM 256
#define BN 256
#define KT 64

typedef __bf16 bf16;
typedef __bf16 bf16x8 __attribute__((ext_vector_type(8)));
typedef __bf16 bf16x4 __attribute__((ext_vector_type(4)));
typedef float f32x4 __attribute__((ext_vector_type(4)));

#define BAR() asm volatile("s_barrier" ::: "memory")

// branchless insert into ascending sorted-8 list (drops the largest)
__device__ __forceinline__ void ins8(float (&lst)[8], float d) {
  float c = d;
  #pragma unroll
  for (int i = 0; i < 8; ++i) {
    float lo = fminf(lst[i], c);
    c = fmaxf(lst[i], c);
    lst[i] = lo;
  }
}

__device__ __forceinline__ void gload_lds16(const void* g, void* l) {
  __builtin_amdgcn_global_load_lds(
      (const __attribute__((address_space(1))) void*)g,
      (__attribute__((address_space(3))) void*)l, 16, 0, 0);
}

// ---- prep: norms + bf16 convert (+norm-digit bake) + min_dists->out copy ---
// x rows -> xb[r][0..1023]=bf16(x), [1024..1027]=[hx,lx,1,1]
// y rows -> yb[c][0..1023]=bf16(-2y), [1024..1027]=[1,1,hy,ly]
// => MFMA dot over 1088 = x2 + y2 - 2 x.y  (squared distance, direct)
template<bool PRE>
__global__ void prep_kernel(const float* __restrict__ x, const float* __restrict__ y,
                            float* __restrict__ x2, float* __restrict__ y2,
                            bf16* __restrict__ xb, bf16* __restrict__ yb,
                            const float4* __restrict__ mind4, float4* __restrict__ out4,
                            int n4, int B, int M, int nNormBlocks) {
  if ((int)blockIdx.x >= nNormBlocks) {        // tail blocks: full-buffer copy
    int i = ((int)blockIdx.x - nNormBlocks) * 256 + threadIdx.x;
    if (i < n4) out4[i] = mind4[i];
    return;
  }
  int wv = threadIdx.x >> 6;
  int lane = threadIdx.x & 63;
  int row = blockIdx.x * 4 + wv;
  const float* src;
  float* dst;
  bf16* bdst;
  bool isY;
  if (row < M) {
    isY = true;
    src = y + (size_t)row * DIMS; dst = y2 + row; bdst = yb + (size_t)row * DEXT;
  } else {
    int r = row - M;
    if (r >= B) return;
    isY = false;
    src = x + (size_t)r * DIMS; dst = x2 + r; bdst = xb + (size_t)r * DEXT;
  }
  const float sgn = isY ? -2.f : 1.f;
  float s = 0.f;
  #pragma unroll
  for (int q = 0; q < DIMS / 4; q += 64) {
    float4 v = ((const float4*)src)[q + lane];
    s = fmaf(v.x, v.x, s); s = fmaf(v.y, v.y, s);
    s = fmaf(v.z, v.z, s); s = fmaf(v.w, v.w, s);
    if (PRE) {
      bf16x4 bv = {(bf16)(sgn * v.x), (bf16)(sgn * v.y),
                   (bf16)(sgn * v.z), (bf16)(sgn * v.w)};
      *(bf16x4*)(bdst + (size_t)(q + lane) * 4) = bv;
    }
  }
  #pragma unroll
  for (int off = 32; off; off >>= 1) s += __shfl_xor(s, off);
  if (lane == 0) *dst = s;
  if (PRE) {
    bf16 h = (bf16)s;
    bf16 lo = (bf16)(s - (float)h);
    bf16 one = (bf16)1.f, zero = (bf16)0.f;
    if (lane < 16) {
      bf16x4 e = {zero, zero, zero, zero};
      if (lane == 0) e = isY ? (bf16x4){one, one, h, lo} : (bf16x4){h, lo, one, one};
      *(bf16x4*)(bdst + DIMS + lane * 4) = e;
    }
  }
}

// ---------------- phase A: 256x256 bf16 MFMA; acc == squared distance ------
// grid 256 blocks (rowblk = bid>>5, colchunk = bid&31); 512 thr = 8 waves 2Mx4N.
// K-loop: r8's 2-phase counted-vmcnt (stage t+1 -> vmcnt(8) -> bar -> 24
// ds_read + 64 MFMA -> bar). Epilogue: pure clamp/mask/transpose/scan.
template<bool PRE>
__global__ __launch_bounds__(512, 2) void knn_fused(
    const float* __restrict__ xf, const float* __restrict__ yf,
    const bf16* __restrict__ xb, const bf16* __restrict__ yb,
    const float* __restrict__ x2, const float* __restrict__ y2,
    float* __restrict__ topk_out,           // [nch][B][8] squared dists
    const int* __restrict__ xsp, const int* __restrict__ ysp,
    int B, int M, int nch) {
  __shared__ __align__(16) char smem[131072]; // 2 x (A 32KB + B 32KB); epilogue reuse
  float* eps = (float*)smem;                  // [128 rows][64 blk of f32x4], rotated
  float* part = (float*)smem;                 // [2][512][9] partial top-8s

  const int tid = threadIdx.x;
  const int wv = tid >> 6;
  const int l = tid & 63;
  const int wr = wv >> 2, wc = wv & 3;
  const int g4 = l >> 4, l16 = l & 15;
  const int rowblk = blockIdx.x >> 5, colchunk = blockIdx.x & 31;
  const int r0 = rowblk * BM;
  const int c0 = colchunk * BN;
  const int xs = *xsp, ys = *ysp;
  const float FINF = __builtin_inff();

  f32x4 acc[8][4];
  #pragma unroll
  for (int mi = 0; mi < 8; ++mi)
    #pragma unroll
    for (int ni = 0; ni < 4; ++ni)
      acc[mi][ni] = (f32x4){0.f, 0.f, 0.f, 0.f};

  auto STAGE_A = [&](char* buf, int k0) {
    #pragma unroll
    for (int p = 0; p < 4; ++p) {
      int row = p * 64 + (tid >> 3);
      int sl = (tid & 7) ^ (row & 7);        // pre-swizzled global source
      gload_lds16(xb + (size_t)(r0 + row) * DEXT + k0 + sl * 8,
                  buf + p * 8192 + tid * 16);
    }
  };
  auto STAGE_B = [&](char* buf, int k0) {
    #pragma unroll
    for (int p = 0; p < 4; ++p) {
      int row = p * 64 + (tid >> 3);
      int sl = (tid & 7) ^ (row & 7);
      gload_lds16(yb + (size_t)(c0 + row) * DEXT + k0 + sl * 8,
                  buf + p * 8192 + tid * 16);
    }
  };
  // fp32 fallback staging (single buffer, reg convert; K=1024 only)
  auto STAGE_CONV = [&](char* abuf, char* bbuf, int k0) {
    #pragma unroll
    for (int p = 0; p < 4; ++p) {
      int row = p * 64 + (tid >> 3);
      int sl = (tid & 7) ^ (row & 7);
      const float* gx = xf + (size_t)(r0 + row) * DIMS + k0 + sl * 8;
      float4 a0 = *(const float4*)gx, a1 = *(const float4*)(gx + 4);
      *(bf16x8*)(abuf + p * 8192 + tid * 16) =
          (bf16x8){(bf16)a0.x, (bf16)a0.y, (bf16)a0.z, (bf16)a0.w,
                   (bf16)a1.x, (bf16)a1.y, (bf16)a1.z, (bf16)a1.w};
      const float* gy = yf + (size_t)(c0 + row) * DIMS + k0 + sl * 8;
      float4 b0 = *(const float4*)gy, b1 = *(const float4*)(gy + 4);
      *(bf16x8*)(bbuf + p * 8192 + tid * 16) =
          (bf16x8){(bf16)b0.x, (bf16)b0.y, (bf16)b0.z, (bf16)b0.w,
                   (bf16)b1.x, (bf16)b1.y, (bf16)b1.z, (bf16)b1.w};
    }
  };

  auto LDA = [&](bf16x8 (&af)[4][2], const char* xd, int mh) { // 8 ds_read_b128
    #pragma unroll
    for (int mi = 0; mi < 4; ++mi)
      #pragma unroll
      for (int kk = 0; kk < 2; ++kk) {
        int row = wr * 128 + mh * 64 + mi * 16 + l16;
        int phys = (kk * 4 + g4) ^ (row & 7);
        af[mi][kk] = *(const bf16x8*)(xd + row * 128 + phys * 16);
      }
  };
  auto LDB = [&](bf16x8 (&bfr)[2][2], const char* yd, int nh) { // 4 ds_read_b128
    #pragma unroll
    for (int ni = 0; ni < 2; ++ni)
      #pragma unroll
      for (int kk = 0; kk < 2; ++kk) {
        int col = wc * 64 + nh * 32 + ni * 16 + l16;
        int phys = (kk * 4 + g4) ^ (col & 7);
        bfr[ni][kk] = *(const bf16x8*)(yd + col * 128 + phys * 16);
      }
  };

#define MFMAQ(AF, BF, MB, NB)                                               \
  {                                                                         \
    __builtin_amdgcn_s_setprio(1);                                          \
    _Pragma("unroll") for (int mi = 0; mi < 4; ++mi)                        \
      _Pragma("unroll") for (int ni = 0; ni < 2; ++ni)                      \
        _Pragma("unroll") for (int kk = 0; kk < 2; ++kk)                    \
          acc[(MB) + mi][(NB) + ni] = __builtin_amdgcn_mfma_f32_16x16x32_bf16( \
              AF[mi][kk], BF[ni][kk], acc[(MB) + mi][(NB) + ni], 0, 0, 0);  \
    __builtin_amdgcn_s_setprio(0);                                          \
  }

  bf16x8 a0f[4][2], a1f[4][2], b0f[2][2], b1f[2][2];

  if (PRE) {
    const int NTL = DEXT / KT;               // 17 tiles
    STAGE_A(smem, 0);
    STAGE_B(smem + 32768, 0);

    #pragma unroll 1
    for (int t = 0; t < NTL; ++t) {
      const int cur = t & 1;
      const char* xd = smem + cur * 65536;
      const char* yd = xd + 32768;
      char* nx = smem + (cur ^ 1) * 65536;

      if (t + 1 < NTL) {
        STAGE_A(nx, (t + 1) * KT);           // 8 loads -> other buffer
        STAGE_B(nx + 32768, (t + 1) * KT);
        asm volatile("s_waitcnt vmcnt(8)" ::: "memory");  // stage(t) done only
      } else {
        asm volatile("s_waitcnt vmcnt(0)" ::: "memory");
      }
      BAR();                                  // buf[t] visible to all waves

      LDA(a0f, xd, 0); LDB(b0f, yd, 0);
      LDA(a1f, xd, 1); LDB(b1f, yd, 1);
      MFMAQ(a0f, b0f, 0, 0);
      MFMAQ(a1f, b0f, 4, 0);
      MFMAQ(a1f, b1f, 4, 2);
      MFMAQ(a0f, b1f, 0, 2);

      BAR();                                  // all waves done reading buf[t]
    }
  } else {
    #pragma unroll 1
    for (int t = 0; t < DIMS / KT; ++t) {
      __syncthreads();
      STAGE_CONV(smem, smem + 32768, t * KT);
      __syncthreads();
      const char* xd = smem;
      const char* yd = smem + 32768;
      LDA(a0f, xd, 0); LDB(b0f, yd, 0);
      MFMAQ(a0f, b0f, 0, 0);
      LDA(a1f, xd, 1);
      MFMAQ(a1f, b0f, 4, 0);
      LDB(b1f, yd, 1);
      MFMAQ(a1f, b1f, 4, 2);
      MFMAQ(a0f, b1f, 0, 2);
      __syncthreads();
    }
  }

  // ---- epilogue: acc IS the squared distance (PRE). No global loads. ----
  float t8[2][8];
  #pragma unroll
  for (int h = 0; h < 2; ++h) {
    __syncthreads();
    if (wr == h) {                           // 4 waves write 128x256 f32
      #pragma unroll
      for (int mi = 0; mi < 8; ++mi)
        #pragma unroll
        for (int j = 0; j < 4; ++j) {
          int row = mi * 16 + g4 * 4 + j;    // 0..127 within half
          int gr = r0 + h * 128 + row;
          float xv = PRE ? 0.f : x2[gr];
          #pragma unroll
          for (int ni = 0; ni < 4; ++ni) {
            int col = wc * 64 + ni * 16 + l16;
            float sq;
            if (PRE) sq = fmaxf(acc[mi][ni][j], 0.f);
            else     sq = fmaxf(xv + y2[c0 + col] - 2.f * acc[mi][ni][j], 0.f);
            if (xs + gr == ys + c0 + col) sq = FINF;
            int phys = ((col >> 2) + row) & 63;   // additive rotation: 2-way free
            eps[row * 256 + phys * 4 + (col & 3)] = sq;
          }
        }
    }
    __syncthreads();
    {
      int row = tid >> 2, q = tid & 3;       // 4 threads/row, 64 cols each
      #pragma unroll
      for (int k = 0; k < 8; ++k) t8[h][k] = FINF;
      #pragma unroll 4
      for (int i = 0; i < 16; ++i) {
        int phys = (q * 16 + i + row) & 63;
        f32x4 v = *(const f32x4*)&eps[row * 256 + phys * 4];
        if (v[0] < t8[h][7]) ins8(t8[h], v[0]);
        if (v[1] < t8[h][7]) ins8(t8[h], v[1]);
        if (v[2] < t8[h][7]) ins8(t8[h], v[2]);
        if (v[3] < t8[h][7]) ins8(t8[h], v[3]);
      }
    }
  }
  __syncthreads();                           // eps dead; reuse as part[2][512][9]
  #pragma unroll
  for (int h = 0; h < 2; ++h)
    #pragma unroll
    for (int k = 0; k < 8; ++k)
      part[(h * 512 + tid) * 9 + k] = t8[h][k];
  __syncthreads();
  if (tid < 256) {                           // merge 4 quarter-scans per row
    int h = tid >> 7, rl = tid & 127;
    float f8[8];
    #pragma unroll
    for (int k = 0; k < 8; ++k) f8[k] = FINF;
    #pragma unroll
    for (int q = 0; q < 4; ++q)
      #pragma unroll
      for (int v = 0; v < 8; ++v) {
        float d = part[(h * 512 + rl * 4 + q) * 9 + v];
        if (d < f8[7]) ins8(f8, d);
      }
    float* o = topk_out + ((size_t)colchunk * B + (r0 + tid)) * 8;
    #pragma unroll
    for (int k = 0; k < 8; ++k) o[k] = f8[k];
  }
}

// ---------------- phase B: merge chunk candidates + running min_dists ------
__global__ void knn_phaseB(const float* __restrict__ topk,
                           const float* __restrict__ mind_in,
                           float* __restrict__ out,
                           const int* __restrict__ xsp, int B, int nch) {
  int r = blockIdx.x * blockDim.x + threadIdx.x;
  if (r >= B) return;
  int x_start = *xsp;
  const float FINF = __builtin_inff();
  float lst[8];
  #pragma unroll
  for (int k = 0; k < 8; ++k) lst[k] = FINF;
  for (int c = 0; c < nch; ++c) {
    const float* bp = topk + ((size_t)c * B + r) * 8;
    #pragma unroll
    for (int k = 0; k < 8; ++k) {
      float d = sqrtf(bp[k]);                // squared -> distance
      if (d < lst[7]) ins8(lst, d);
    }
  }
  const float* cur = mind_in + (size_t)(x_start + r) * KNN_K;
  #pragma unroll
  for (int k = 0; k < 8; ++k) {
    float d = cur[k];
    if (d < lst[7]) ins8(lst, d);
  }
  #pragma unroll
  for (int k = 0; k < 8; ++k) out[(size_t)(x_start + r) * KNN_K + k] = lst[k];
}

extern "C" void kernel_launch(void* const* d_in, const int* in_sizes, int n_in,
                              void* d_out, int out_size, void* d_ws, size_t ws_size,
                              hipStream_t stream) {
  const float* x = (const float*)d_in[0];
  const float* y = (const float*)d_in[1];
  const float* mind = (const float*)d_in[2];
  const int* xsp = (const int*)d_in[3];
  const int* ysp = (const int*)d_in[4];
  float* out = (float*)d_out;

  const int B = in_sizes[0] / DIMS;       // 2048
  const int M = in_sizes[1] / DIMS;       // 8192
  const int nch = M / BN;                 // 32

  float* y2 = (float*)d_ws;               // [M]
  float* x2 = y2 + M;                     // [B]
  float* topk = x2 + B;                   // [nch][B][8]
  size_t base = ((size_t)(M + B) + (size_t)B * nch * 8) * 4;
  base = (base + 255) & ~(size_t)255;
  bf16* xbw = (bf16*)((char*)d_ws + base);
  bf16* ybw = xbw + (size_t)B * DEXT;
  size_t need = base + ((size_t)B + (size_t)M) * DEXT * 2;
  bool pre = ws_size >= need;

  int nNorm = (B + M + 3) / 4;
  int n4 = out_size / 4;
  int nCopy = (n4 + 255) / 256;
  if (pre)
    prep_kernel<true><<<nNorm + nCopy, 256, 0, stream>>>(
        x, y, x2, y2, xbw, ybw, (const float4*)mind, (float4*)out, n4, B, M, nNorm);
  else
    prep_kernel<false><<<nNorm + nCopy, 256, 0, stream>>>(
        x, y, x2, y2, xbw, ybw, (const float4*)mind, (float4*)out, n4, B, M, nNorm);

  int nBlocks = (B / BM) * nch;           // 8 x 32 = 256 (1 block/CU)
  if (pre)
    knn_fused<true><<<nBlocks, 512, 0, stream>>>(x, y, xbw, ybw, x2, y2, topk, xsp, ysp, B, M, nch);
  else
    knn_fused<false><<<nBlocks, 512, 0, stream>>>(x, y, xbw, ybw, x2, y2, topk, xsp, ysp, B, M, nch);

  knn_phaseB<<<(B + 255) / 256, 256, 0, stream>>>(topk, mind, out, xsp, B, nch);
}

// Round 10
// 80.275 us; speedup vs baseline: 1.6665x; 1.6665x over previous
//
#include <hip/hip_runtime.h>

#define DIMS 1024
#define DEXT 1088        // DIMS + 64: extra K-tile carrying [h,l,1,1] norm digits
#define KNN_K 8
#define BM 128
#define BN 128
#define KT 64

typedef __bf16 bf16;
typedef __bf16 bf16x8 __attribute__((ext_vector_type(8)));
typedef __bf16 bf16x4 __attribute__((ext_vector_type(4)));
typedef float f32x4 __attribute__((ext_vector_type(4)));

// branchless insert into ascending sorted-8 list (drops the largest)
__device__ __forceinline__ void ins8(float (&lst)[8], float d) {
  float c = d;
  #pragma unroll
  for (int i = 0; i < 8; ++i) {
    float lo = fminf(lst[i], c);
    c = fmaxf(lst[i], c);
    lst[i] = lo;
  }
}

__device__ __forceinline__ void gload_lds16(const void* g, void* l) {
  __builtin_amdgcn_global_load_lds(
      (const __attribute__((address_space(1))) void*)g,
      (__attribute__((address_space(3))) void*)l, 16, 0, 0);
}

// ---- prep: norms + bf16 convert (+norm-digit bake) + min_dists->out copy ---
// x rows -> xb[r][0..1023]=bf16(x), [1024..1027]=[hx,lx,1,1]
// y rows -> yb[c][0..1023]=bf16(-2y), [1024..1027]=[1,1,hy,ly]
// => MFMA dot over 1088 = x2 + y2 - 2 x.y  (squared distance, direct)
template<bool PRE>
__global__ void prep_kernel(const float* __restrict__ x, const float* __restrict__ y,
                            float* __restrict__ x2, float* __restrict__ y2,
                            bf16* __restrict__ xb, bf16* __restrict__ yb,
                            const float4* __restrict__ mind4, float4* __restrict__ out4,
                            int n4, int B, int M, int nNormBlocks) {
  if ((int)blockIdx.x >= nNormBlocks) {        // tail blocks: full-buffer copy
    int i = ((int)blockIdx.x - nNormBlocks) * 256 + threadIdx.x;
    if (i < n4) out4[i] = mind4[i];
    return;
  }
  int wv = threadIdx.x >> 6;
  int lane = threadIdx.x & 63;
  int row = blockIdx.x * 4 + wv;
  const float* src;
  float* dst;
  bf16* bdst;
  bool isY;
  if (row < M) {
    isY = true;
    src = y + (size_t)row * DIMS; dst = y2 + row; bdst = yb + (size_t)row * DEXT;
  } else {
    int r = row - M;
    if (r >= B) return;
    isY = false;
    src = x + (size_t)r * DIMS; dst = x2 + r; bdst = xb + (size_t)r * DEXT;
  }
  const float sgn = isY ? -2.f : 1.f;
  float s = 0.f;
  #pragma unroll
  for (int q = 0; q < DIMS / 4; q += 64) {
    float4 v = ((const float4*)src)[q + lane];
    s = fmaf(v.x, v.x, s); s = fmaf(v.y, v.y, s);
    s = fmaf(v.z, v.z, s); s = fmaf(v.w, v.w, s);
    if (PRE) {
      bf16x4 bv = {(bf16)(sgn * v.x), (bf16)(sgn * v.y),
                   (bf16)(sgn * v.z), (bf16)(sgn * v.w)};
      *(bf16x4*)(bdst + (size_t)(q + lane) * 4) = bv;
    }
  }
  #pragma unroll
  for (int off = 32; off; off >>= 1) s += __shfl_xor(s, off);
  if (lane == 0) *dst = s;
  if (PRE) {
    bf16 h = (bf16)s;
    bf16 lo = (bf16)(s - (float)h);
    bf16 one = (bf16)1.f, zero = (bf16)0.f;
    if (lane < 16) {
      bf16x4 e = {zero, zero, zero, zero};
      if (lane == 0) e = isY ? (bf16x4){one, one, h, lo} : (bf16x4){h, lo, one, one};
      *(bf16x4*)(bdst + DIMS + lane * 4) = e;
    }
  }
}

// ---------------- phase A: m97-structure 128x128 bf16 MFMA, 4 blocks/CU ----
// grid 1024 blocks (rowblk = bid>>6, colchunk = bid&63); 256 thr = 4 waves 2x2.
// Per wave 64x64 (acc[4][4] f32x4). Single-buffer LDS, 2 barriers/K-tile;
// cross-block wave overlap hides the stage drain (m97/m114 mechanism).
template<bool PRE>
__global__ __launch_bounds__(256, 4) void knn_m97(
    const float* __restrict__ xf, const float* __restrict__ yf,
    const bf16* __restrict__ xb, const bf16* __restrict__ yb,
    const float* __restrict__ x2, const float* __restrict__ y2,
    float* __restrict__ topk_out,           // [nch][B][8] squared dists
    const int* __restrict__ xsp, const int* __restrict__ ysp,
    int B, int M, int nch) {
  __shared__ __align__(16) char smem[33792]; // A 16KB + B 16KB; epilogue [64][130] f32
  bf16* As = (bf16*)smem;
  bf16* Bs = (bf16*)(smem + 16384);
  float* eps = (float*)smem;

  const int tid = threadIdx.x;
  const int wv = tid >> 6, l = tid & 63;
  const int wr = wv >> 1, wc = wv & 1;
  const int g4 = l >> 4, l16 = l & 15;
  const int rowblk = blockIdx.x >> 6, colchunk = blockIdx.x & 63;
  const int r0 = rowblk * BM, c0 = colchunk * BN;
  const int xs = *xsp, ys = *ysp;
  const float FINF = __builtin_inff();

  f32x4 acc[4][4];
  #pragma unroll
  for (int mi = 0; mi < 4; ++mi)
    #pragma unroll
    for (int ni = 0; ni < 4; ++ni)
      acc[mi][ni] = (f32x4){0.f, 0.f, 0.f, 0.f};

  const int NTL = PRE ? (DEXT / KT) : (DIMS / KT);

  for (int t = 0; t < NTL; ++t) {
    __syncthreads();                         // prev tile's readers done
    if (PRE) {
      #pragma unroll
      for (int p = 0; p < 4; ++p) {          // A tile [128][64] bf16
        int row = p * 32 + (tid >> 3);
        int cs = (tid & 7) ^ (row & 7);      // pre-swizzled global source
        gload_lds16(xb + (size_t)(r0 + row) * DEXT + t * KT + cs * 8,
                    (char*)As + p * 4096 + tid * 16);
      }
      #pragma unroll
      for (int p = 0; p < 4; ++p) {          // B tile
        int row = p * 32 + (tid >> 3);
        int cs = (tid & 7) ^ (row & 7);
        gload_lds16(yb + (size_t)(c0 + row) * DEXT + t * KT + cs * 8,
                    (char*)Bs + p * 4096 + tid * 16);
      }
    } else {
      #pragma unroll
      for (int p = 0; p < 4; ++p) {
        int row = p * 32 + (tid >> 3);
        int sl = tid & 7;
        const float* gx = xf + (size_t)(r0 + row) * DIMS + t * KT + sl * 8;
        float4 a0 = *(const float4*)gx, a1 = *(const float4*)(gx + 4);
        *(bf16x8*)((char*)As + row * 128 + ((sl ^ (row & 7)) * 16)) =
            (bf16x8){(bf16)a0.x, (bf16)a0.y, (bf16)a0.z, (bf16)a0.w,
                     (bf16)a1.x, (bf16)a1.y, (bf16)a1.z, (bf16)a1.w};
        const float* gy = yf + (size_t)(c0 + row) * DIMS + t * KT + sl * 8;
        float4 b0 = *(const float4*)gy, b1 = *(const float4*)(gy + 4);
        *(bf16x8*)((char*)Bs + row * 128 + ((sl ^ (row & 7)) * 16)) =
            (bf16x8){(bf16)b0.x, (bf16)b0.y, (bf16)b0.z, (bf16)b0.w,
                     (bf16)b1.x, (bf16)b1.y, (bf16)b1.z, (bf16)b1.w};
      }
    }
    __syncthreads();                         // tile staged (vmcnt drained here)

    #pragma unroll
    for (int kk = 0; kk < 2; ++kk) {
      bf16x8 af[4], bfr[4];
      #pragma unroll
      for (int mi = 0; mi < 4; ++mi) {
        int row = wr * 64 + mi * 16 + l16;
        int phys = (kk * 4 + g4) ^ (row & 7);
        af[mi] = *(const bf16x8*)((char*)As + row * 128 + phys * 16);
      }
      #pragma unroll
      for (int ni = 0; ni < 4; ++ni) {
        int col = wc * 64 + ni * 16 + l16;
        int phys = (kk * 4 + g4) ^ (col & 7);
        bfr[ni] = *(const bf16x8*)((char*)Bs + col * 128 + phys * 16);
      }
      #pragma unroll
      for (int mi = 0; mi < 4; ++mi)
        #pragma unroll
        for (int ni = 0; ni < 4; ++ni)
          acc[mi][ni] = __builtin_amdgcn_mfma_f32_16x16x32_bf16(
              af[mi], bfr[ni], acc[mi][ni], 0, 0, 0);
    }
  }

  // ---- epilogue: 2 halves of 64 rows via eps [64][130]; shfl merge --------
  #pragma unroll
  for (int h = 0; h < 2; ++h) {
    __syncthreads();                         // LDS free (staging / prev half done)
    if (wr == h) {                           // waves (h,0),(h,1) write 64x128
      #pragma unroll
      for (int mi = 0; mi < 4; ++mi)
        #pragma unroll
        for (int j = 0; j < 4; ++j) {
          int row = mi * 16 + g4 * 4 + j;    // 0..63 within half
          int gr = r0 + h * 64 + row;
          float xv = PRE ? 0.f : x2[gr];
          #pragma unroll
          for (int ni = 0; ni < 4; ++ni) {
            int col = wc * 64 + ni * 16 + l16;
            float sq;
            if (PRE) sq = fmaxf(acc[mi][ni][j], 0.f);
            else     sq = fmaxf(xv + y2[c0 + col] - 2.f * acc[mi][ni][j], 0.f);
            if (xs + gr == ys + c0 + col) sq = FINF;
            eps[row * 130 + col] = sq;
          }
        }
    }
    __syncthreads();
    {
      int row = tid >> 2, q = tid & 3;       // 4 lanes/row, 32 cols each
      float t8[8];
      #pragma unroll
      for (int k = 0; k < 8; ++k) t8[k] = FINF;
      #pragma unroll
      for (int i = 0; i < 8; ++i) {
        f32x4 v = *(const f32x4*)&eps[row * 130 + q * 32 + i * 4];
        if (v[0] < t8[7]) ins8(t8, v[0]);
        if (v[1] < t8[7]) ins8(t8, v[1]);
        if (v[2] < t8[7]) ins8(t8, v[2]);
        if (v[3] < t8[7]) ins8(t8, v[3]);
      }
      #pragma unroll
      for (int off = 1; off <= 2; off <<= 1)   // merge the 4 q-lanes
        #pragma unroll
        for (int k = 0; k < 8; ++k) {
          float v = __shfl_xor(t8[k], off);
          if (v < t8[7]) ins8(t8, v);
        }
      if (q == 0) {
        float* o = topk_out + ((size_t)colchunk * B + (r0 + h * 64 + row)) * 8;
        #pragma unroll
        for (int k = 0; k < 8; ++k) o[k] = t8[k];
      }
    }
  }
}

// ---------------- phase B: wave-per-row merge of nch chunk lists -----------
__global__ void knn_phaseB(const float* __restrict__ topk,
                           const float* __restrict__ mind_in,
                           float* __restrict__ out,
                           const int* __restrict__ xsp, int B, int nch) {
  int w = threadIdx.x >> 6, lane = threadIdx.x & 63;
  int r = blockIdx.x * 4 + w;
  if (r >= B) return;
  int x_start = *xsp;
  const float FINF = __builtin_inff();
  float t8[8];
  #pragma unroll
  for (int k = 0; k < 8; ++k) t8[k] = FINF;
  for (int c = lane; c < nch; c += 64) {     // one chunk list per lane
    const float* bp = topk + ((size_t)c * B + r) * 8;
    f32x4 v0 = *(const f32x4*)bp;
    f32x4 v1 = *(const f32x4*)(bp + 4);
    if (v0[0] < t8[7]) ins8(t8, v0[0]);
    if (v0[1] < t8[7]) ins8(t8, v0[1]);
    if (v0[2] < t8[7]) ins8(t8, v0[2]);
    if (v0[3] < t8[7]) ins8(t8, v0[3]);
    if (v1[0] < t8[7]) ins8(t8, v1[0]);
    if (v1[1] < t8[7]) ins8(t8, v1[1]);
    if (v1[2] < t8[7]) ins8(t8, v1[2]);
    if (v1[3] < t8[7]) ins8(t8, v1[3]);
  }
  #pragma unroll
  for (int off = 32; off >= 1; off >>= 1)    // wave butterfly merge
    #pragma unroll
    for (int k = 0; k < 8; ++k) {
      float v = __shfl_xor(t8[k], off);
      if (v < t8[7]) ins8(t8, v);
    }
  if (lane == 0) {
    float lst[8];
    #pragma unroll
    for (int k = 0; k < 8; ++k) lst[k] = sqrtf(t8[k]);  // squared -> distance
    const float* cur = mind_in + (size_t)(x_start + r) * KNN_K;
    #pragma unroll
    for (int k = 0; k < 8; ++k) {
      float d = cur[k];
      if (d < lst[7]) ins8(lst, d);
    }
    #pragma unroll
    for (int k = 0; k < 8; ++k) out[(size_t)(x_start + r) * KNN_K + k] = lst[k];
  }
}

extern "C" void kernel_launch(void* const* d_in, const int* in_sizes, int n_in,
                              void* d_out, int out_size, void* d_ws, size_t ws_size,
                              hipStream_t stream) {
  const float* x = (const float*)d_in[0];
  const float* y = (const float*)d_in[1];
  const float* mind = (const float*)d_in[2];
  const int* xsp = (const int*)d_in[3];
  const int* ysp = (const int*)d_in[4];
  float* out = (float*)d_out;

  const int B = in_sizes[0] / DIMS;       // 2048
  const int M = in_sizes[1] / DIMS;       // 8192
  const int nch = M / BN;                 // 64

  float* y2 = (float*)d_ws;               // [M]
  float* x2 = y2 + M;                     // [B]
  float* topk = x2 + B;                   // [nch][B][8]
  size_t base = ((size_t)(M + B) + (size_t)B * nch * 8) * 4;
  base = (base + 255) & ~(size_t)255;
  bf16* xbw = (bf16*)((char*)d_ws + base);
  bf16* ybw = xbw + (size_t)B * DEXT;
  size_t need = base + ((size_t)B + (size_t)M) * DEXT * 2;
  bool pre = ws_size >= need;

  int nNorm = (B + M + 3) / 4;
  int n4 = out_size / 4;
  int nCopy = (n4 + 255) / 256;
  if (pre)
    prep_kernel<true><<<nNorm + nCopy, 256, 0, stream>>>(
        x, y, x2, y2, xbw, ybw, (const float4*)mind, (float4*)out, n4, B, M, nNorm);
  else
    prep_kernel<false><<<nNorm + nCopy, 256, 0, stream>>>(
        x, y, x2, y2, xbw, ybw, (const float4*)mind, (float4*)out, n4, B, M, nNorm);

  int nBlocks = (B / BM) * nch;           // 16 x 64 = 1024 (4 blocks/CU)
  if (pre)
    knn_m97<true><<<nBlocks, 256, 0, stream>>>(x, y, xbw, ybw, x2, y2, topk, xsp, ysp, B, M, nch);
  else
    knn_m97<false><<<nBlocks, 256, 0, stream>>>(x, y, xbw, ybw, x2, y2, topk, xsp, ysp, B, M, nch);

  knn_phaseB<<<(B + 3) / 4, 256, 0, stream>>>(topk, mind, out, xsp, B, nch);
}

// Round 11
// 62.935 us; speedup vs baseline: 2.1257x; 1.2755x over previous
//
#include <hip/hip_runtime.h>

#define DIMS 1024
#define DEXT 1088        // DIMS + 64: extra K-tile carrying [h,l,1,1] norm digits
#define KNN_K 8
#define BM 128
#define BN 128
#define KT 64

typedef __bf16 bf16;
typedef __bf16 bf16x8 __attribute__((ext_vector_type(8)));
typedef __bf16 bf16x4 __attribute__((ext_vector_type(4)));
typedef float f32x4 __attribute__((ext_vector_type(4)));

// compare-exchange (ascending)
__device__ __forceinline__ void ce(float& a, float& b) {
  float lo = fminf(a, b), hi = fmaxf(a, b); a = lo; b = hi;
}
// Batcher odd-even merge sort, 8 elements ascending (19 CE, branch-free)
__device__ __forceinline__ void sort8(float (&v)[8]) {
  ce(v[0],v[1]); ce(v[2],v[3]); ce(v[4],v[5]); ce(v[6],v[7]);
  ce(v[0],v[2]); ce(v[1],v[3]); ce(v[4],v[6]); ce(v[5],v[7]);
  ce(v[1],v[2]); ce(v[5],v[6]);
  ce(v[0],v[4]); ce(v[1],v[5]); ce(v[2],v[6]); ce(v[3],v[7]);
  ce(v[2],v[4]); ce(v[3],v[5]);
  ce(v[1],v[2]); ce(v[3],v[4]); ce(v[5],v[6]);
}
// a,b ascending sorted-8 -> a = smallest 8 of union, ascending (8 min + 12 CE)
__device__ __forceinline__ void merge8(float (&a)[8], const float (&b)[8]) {
  float u[8];
  #pragma unroll
  for (int k = 0; k < 8; ++k) u[k] = fminf(a[k], b[7 - k]);  // bitonic
  ce(u[0],u[4]); ce(u[1],u[5]); ce(u[2],u[6]); ce(u[3],u[7]);
  ce(u[0],u[2]); ce(u[1],u[3]); ce(u[4],u[6]); ce(u[5],u[7]);
  ce(u[0],u[1]); ce(u[2],u[3]); ce(u[4],u[5]); ce(u[6],u[7]);
  #pragma unroll
  for (int k = 0; k < 8; ++k) a[k] = u[k];
}

__device__ __forceinline__ void gload_lds16(const void* g, void* l) {
  __builtin_amdgcn_global_load_lds(
      (const __attribute__((address_space(1))) void*)g,
      (__attribute__((address_space(3))) void*)l, 16, 0, 0);
}

// ---- prep: norms + bf16 convert (+norm-digit bake) + min_dists->out copy ---
// x rows -> xb[r][0..1023]=bf16(x), [1024..1027]=[hx,lx,1,1]
// y rows -> yb[c][0..1023]=bf16(-2y), [1024..1027]=[1,1,hy,ly]
// => MFMA dot over 1088 = x2 + y2 - 2 x.y  (squared distance, direct)
template<bool PRE>
__global__ void prep_kernel(const float* __restrict__ x, const float* __restrict__ y,
                            float* __restrict__ x2, float* __restrict__ y2,
                            bf16* __restrict__ xb, bf16* __restrict__ yb,
                            const float4* __restrict__ mind4, float4* __restrict__ out4,
                            int n4, int B, int M, int nNormBlocks) {
  if ((int)blockIdx.x >= nNormBlocks) {        // tail blocks: full-buffer copy
    int i = ((int)blockIdx.x - nNormBlocks) * 256 + threadIdx.x;
    if (i < n4) out4[i] = mind4[i];
    return;
  }
  int wv = threadIdx.x >> 6;
  int lane = threadIdx.x & 63;
  int row = blockIdx.x * 4 + wv;
  const float* src;
  float* dst;
  bf16* bdst;
  bool isY;
  if (row < M) {
    isY = true;
    src = y + (size_t)row * DIMS; dst = y2 + row; bdst = yb + (size_t)row * DEXT;
  } else {
    int r = row - M;
    if (r >= B) return;
    isY = false;
    src = x + (size_t)r * DIMS; dst = x2 + r; bdst = xb + (size_t)r * DEXT;
  }
  const float sgn = isY ? -2.f : 1.f;
  float s = 0.f;
  #pragma unroll
  for (int q = 0; q < DIMS / 4; q += 64) {
    float4 v = ((const float4*)src)[q + lane];
    s = fmaf(v.x, v.x, s); s = fmaf(v.y, v.y, s);
    s = fmaf(v.z, v.z, s); s = fmaf(v.w, v.w, s);
    if (PRE) {
      bf16x4 bv = {(bf16)(sgn * v.x), (bf16)(sgn * v.y),
                   (bf16)(sgn * v.z), (bf16)(sgn * v.w)};
      *(bf16x4*)(bdst + (size_t)(q + lane) * 4) = bv;
    }
  }
  #pragma unroll
  for (int off = 32; off; off >>= 1) s += __shfl_xor(s, off);
  if (lane == 0) *dst = s;
  if (PRE) {
    bf16 h = (bf16)s;
    bf16 lo = (bf16)(s - (float)h);
    bf16 one = (bf16)1.f, zero = (bf16)0.f;
    if (lane < 16) {
      bf16x4 e = {zero, zero, zero, zero};
      if (lane == 0) e = isY ? (bf16x4){one, one, h, lo} : (bf16x4){h, lo, one, one};
      *(bf16x4*)(bdst + DIMS + lane * 4) = e;
    }
  }
}

// ---------------- phase A: m97-structure 128x128, swapped-operand MFMA -----
// grid 1024 blocks; 256 thr = 4 waves 2x2; per wave 64x64.
// mfma(B,A): lane l holds x-rows {mi*16+l16} x y-cols {ni*16+g4*4+j} ->
// per-row top-8 entirely in registers (sorting networks + shfl butterfly).
template<bool PRE>
__global__ __launch_bounds__(256, 4) void knn_m97s(
    const float* __restrict__ xf, const float* __restrict__ yf,
    const bf16* __restrict__ xb, const bf16* __restrict__ yb,
    const float* __restrict__ x2, const float* __restrict__ y2,
    float* __restrict__ topk_out,           // [nch][B][8] squared dists
    const int* __restrict__ xsp, const int* __restrict__ ysp,
    int B, int M, int nch) {
  __shared__ __align__(16) char smem[32768]; // A 16KB + B 16KB; 4KB reused at end
  bf16* As = (bf16*)smem;
  bf16* Bs = (bf16*)(smem + 16384);

  const int tid = threadIdx.x;
  const int wv = tid >> 6, l = tid & 63;
  const int wr = wv >> 1, wc = wv & 1;
  const int g4 = l >> 4, l16 = l & 15;
  const int rowblk = blockIdx.x >> 6, colchunk = blockIdx.x & 63;
  const int r0 = rowblk * BM, c0 = colchunk * BN;
  const int xs = *xsp, ys = *ysp;
  const float FINF = __builtin_inff();

  f32x4 acc[4][4];
  #pragma unroll
  for (int mi = 0; mi < 4; ++mi)
    #pragma unroll
    for (int ni = 0; ni < 4; ++ni)
      acc[mi][ni] = (f32x4){0.f, 0.f, 0.f, 0.f};

  const int NTL = PRE ? (DEXT / KT) : (DIMS / KT);

  for (int t = 0; t < NTL; ++t) {
    __syncthreads();                         // prev tile's readers done
    if (PRE) {
      #pragma unroll
      for (int p = 0; p < 4; ++p) {          // A tile [128][64] bf16
        int row = p * 32 + (tid >> 3);
        int cs = (tid & 7) ^ (row & 7);      // pre-swizzled global source
        gload_lds16(xb + (size_t)(r0 + row) * DEXT + t * KT + cs * 8,
                    (char*)As + p * 4096 + tid * 16);
      }
      #pragma unroll
      for (int p = 0; p < 4; ++p) {          // B tile
        int row = p * 32 + (tid >> 3);
        int cs = (tid & 7) ^ (row & 7);
        gload_lds16(yb + (size_t)(c0 + row) * DEXT + t * KT + cs * 8,
                    (char*)Bs + p * 4096 + tid * 16);
      }
    } else {
      #pragma unroll
      for (int p = 0; p < 4; ++p) {
        int row = p * 32 + (tid >> 3);
        int sl = tid & 7;
        const float* gx = xf + (size_t)(r0 + row) * DIMS + t * KT + sl * 8;
        float4 a0 = *(const float4*)gx, a1 = *(const float4*)(gx + 4);
        *(bf16x8*)((char*)As + row * 128 + ((sl ^ (row & 7)) * 16)) =
            (bf16x8){(bf16)a0.x, (bf16)a0.y, (bf16)a0.z, (bf16)a0.w,
                     (bf16)a1.x, (bf16)a1.y, (bf16)a1.z, (bf16)a1.w};
        const float* gy = yf + (size_t)(c0 + row) * DIMS + t * KT + sl * 8;
        float4 b0 = *(const float4*)gy, b1 = *(const float4*)(gy + 4);
        *(bf16x8*)((char*)Bs + row * 128 + ((sl ^ (row & 7)) * 16)) =
            (bf16x8){(bf16)b0.x, (bf16)b0.y, (bf16)b0.z, (bf16)b0.w,
                     (bf16)b1.x, (bf16)b1.y, (bf16)b1.z, (bf16)b1.w};
      }
    }
    __syncthreads();                         // tile staged (vmcnt drained here)

    #pragma unroll
    for (int kk = 0; kk < 2; ++kk) {
      bf16x8 af[4], bfr[4];
      #pragma unroll
      for (int mi = 0; mi < 4; ++mi) {
        int row = wr * 64 + mi * 16 + l16;
        int phys = (kk * 4 + g4) ^ (row & 7);
        af[mi] = *(const bf16x8*)((char*)As + row * 128 + phys * 16);
      }
      #pragma unroll
      for (int ni = 0; ni < 4; ++ni) {
        int col = wc * 64 + ni * 16 + l16;
        int phys = (kk * 4 + g4) ^ (col & 7);
        bfr[ni] = *(const bf16x8*)((char*)Bs + col * 128 + phys * 16);
      }
      #pragma unroll
      for (int mi = 0; mi < 4; ++mi)
        #pragma unroll
        for (int ni = 0; ni < 4; ++ni)
          acc[mi][ni] = __builtin_amdgcn_mfma_f32_16x16x32_bf16(
              bfr[ni], af[mi], acc[mi][ni], 0, 0, 0);   // SWAPPED: C[ycol][xrow]
    }
  }

  // ---- epilogue: per-lane in-register top-8 (no LDS eps, no divergence) ---
  // lane holds x-rows gr(mi)=r0+wr*64+mi*16+l16; y-cols cb+ni*16+j where
  // cb = c0+wc*64+g4*4. acc[mi][ni][j] = squared distance (PRE).
  const int cb = c0 + wc * 64 + g4 * 4;
  float y2v[16];
  if (!PRE) {
    #pragma unroll
    for (int ni = 0; ni < 4; ++ni)
      #pragma unroll
      for (int j = 0; j < 4; ++j)
        y2v[ni * 4 + j] = y2[cb + ni * 16 + j];
  }

  float t8[4][8];
  #pragma unroll
  for (int mi = 0; mi < 4; ++mi) {
    const int gr = r0 + wr * 64 + mi * 16 + l16;
    const int dmi = xs + gr - ys - cb;       // equals ni*16+j iff self-pair
    const float xv = PRE ? 0.f : x2[gr];
    float a[8], b[8];
    #pragma unroll
    for (int ni = 0; ni < 2; ++ni)
      #pragma unroll
      for (int j = 0; j < 4; ++j) {
        float sq = PRE ? fmaxf(acc[mi][ni][j], 0.f)
                       : fmaxf(xv + y2v[ni * 4 + j] - 2.f * acc[mi][ni][j], 0.f);
        if (dmi == ni * 16 + j) sq = FINF;
        a[ni * 4 + j] = sq;
      }
    #pragma unroll
    for (int ni = 2; ni < 4; ++ni)
      #pragma unroll
      for (int j = 0; j < 4; ++j) {
        float sq = PRE ? fmaxf(acc[mi][ni][j], 0.f)
                       : fmaxf(xv + y2v[ni * 4 + j] - 2.f * acc[mi][ni][j], 0.f);
        if (dmi == ni * 16 + j) sq = FINF;
        b[(ni - 2) * 4 + j] = sq;
      }
    sort8(a); sort8(b); merge8(a, b);        // top8 of lane's 16, ascending
    #pragma unroll
    for (int k = 0; k < 8; ++k) b[k] = __shfl_xor(a[k], 16);
    merge8(a, b);                            // merge g4 pairs
    #pragma unroll
    for (int k = 0; k < 8; ++k) b[k] = __shfl_xor(a[k], 32);
    merge8(a, b);                            // all 4 g4 groups merged
    #pragma unroll
    for (int k = 0; k < 8; ++k) t8[mi][k] = a[k];
  }

  // merge the two wc strips via a 4KB LDS hop -> one chunk per 128 cols
  float* xbuf = (float*)smem;                // [2][4][16][8] f32 = 4KB
  __syncthreads();                           // all K-loop LDS reads done
  if (wc == 1 && g4 == 0) {
    #pragma unroll
    for (int mi = 0; mi < 4; ++mi) {
      float* p = xbuf + ((wr * 4 + mi) * 16 + l16) * 8;
      *(f32x4*)p       = (f32x4){t8[mi][0], t8[mi][1], t8[mi][2], t8[mi][3]};
      *((f32x4*)p + 1) = (f32x4){t8[mi][4], t8[mi][5], t8[mi][6], t8[mi][7]};
    }
  }
  __syncthreads();
  if (wc == 0 && g4 == 0) {
    #pragma unroll
    for (int mi = 0; mi < 4; ++mi) {
      const float* p = xbuf + ((wr * 4 + mi) * 16 + l16) * 8;
      float b[8];
      #pragma unroll
      for (int k = 0; k < 8; ++k) b[k] = p[k];
      merge8(t8[mi], b);
      int gr = r0 + wr * 64 + mi * 16 + l16;
      float* o = topk_out + ((size_t)colchunk * B + gr) * 8;
      *(f32x4*)o       = (f32x4){t8[mi][0], t8[mi][1], t8[mi][2], t8[mi][3]};
      *((f32x4*)o + 1) = (f32x4){t8[mi][4], t8[mi][5], t8[mi][6], t8[mi][7]};
    }
  }
}

// ---------------- phase B: wave-per-row merge of nch sorted lists ----------
__global__ void knn_phaseB(const float* __restrict__ topk,
                           const float* __restrict__ mind_in,
                           float* __restrict__ out,
                           const int* __restrict__ xsp, int B, int nch) {
  int w = threadIdx.x >> 6, lane = threadIdx.x & 63;
  int r = blockIdx.x * 4 + w;
  if (r >= B) return;
  int x_start = *xsp;
  const float* bp = topk + ((size_t)lane * B + r) * 8;   // chunk = lane (nch=64)
  float t8[8];
  f32x4 v0 = *(const f32x4*)bp;
  f32x4 v1 = *(const f32x4*)(bp + 4);
  t8[0]=v0[0]; t8[1]=v0[1]; t8[2]=v0[2]; t8[3]=v0[3];
  t8[4]=v1[0]; t8[5]=v1[1]; t8[6]=v1[2]; t8[7]=v1[3];   // ascending already
  #pragma unroll
  for (int off = 32; off >= 1; off >>= 1) {              // butterfly merge
    float b[8];
    #pragma unroll
    for (int k = 0; k < 8; ++k) b[k] = __shfl_xor(t8[k], off);
    merge8(t8, b);
  }
  if (lane == 0) {
    float lst[8];
    #pragma unroll
    for (int k = 0; k < 8; ++k) lst[k] = sqrtf(t8[k]);   // squared -> distance
    float cur[8];
    const float* cp = mind_in + (size_t)(x_start + r) * KNN_K;
    #pragma unroll
    for (int k = 0; k < 8; ++k) cur[k] = cp[k];
    sort8(cur);
    merge8(lst, cur);
    #pragma unroll
    for (int k = 0; k < 8; ++k) out[(size_t)(x_start + r) * KNN_K + k] = lst[k];
  }
}

extern "C" void kernel_launch(void* const* d_in, const int* in_sizes, int n_in,
                              void* d_out, int out_size, void* d_ws, size_t ws_size,
                              hipStream_t stream) {
  const float* x = (const float*)d_in[0];
  const float* y = (const float*)d_in[1];
  const float* mind = (const float*)d_in[2];
  const int* xsp = (const int*)d_in[3];
  const int* ysp = (const int*)d_in[4];
  float* out = (float*)d_out;

  const int B = in_sizes[0] / DIMS;       // 2048
  const int M = in_sizes[1] / DIMS;       // 8192
  const int nch = M / BN;                 // 64

  float* y2 = (float*)d_ws;               // [M]
  float* x2 = y2 + M;                     // [B]
  float* topk = x2 + B;                   // [nch][B][8]
  size_t base = ((size_t)(M + B) + (size_t)B * nch * 8) * 4;
  base = (base + 255) & ~(size_t)255;
  bf16* xbw = (bf16*)((char*)d_ws + base);
  bf16* ybw = xbw + (size_t)B * DEXT;
  size_t need = base + ((size_t)B + (size_t)M) * DEXT * 2;
  bool pre = ws_size >= need;

  int nNorm = (B + M + 3) / 4;
  int n4 = out_size / 4;
  int nCopy = (n4 + 255) / 256;
  if (pre)
    prep_kernel<true><<<nNorm + nCopy, 256, 0, stream>>>(
        x, y, x2, y2, xbw, ybw, (const float4*)mind, (float4*)out, n4, B, M, nNorm);
  else
    prep_kernel<false><<<nNorm + nCopy, 256, 0, stream>>>(
        x, y, x2, y2, xbw, ybw, (const float4*)mind, (float4*)out, n4, B, M, nNorm);

  int nBlocks = (B / BM) * nch;           // 16 x 64 = 1024 (4 blocks/CU)
  if (pre)
    knn_m97s<true><<<nBlocks, 256, 0, stream>>>(x, y, xbw, ybw, x2, y2, topk, xsp, ysp, B, M, nch);
  else
    knn_m97s<false><<<nBlocks, 256, 0, stream>>>(x, y, xbw, ybw, x2, y2, topk, xsp, ysp, B, M, nch);

  knn_phaseB<<<(B + 3) / 4, 256, 0, stream>>>(topk, mind, out, xsp, B, nch);
}

// Round 12
// 53.433 us; speedup vs baseline: 2.5037x; 1.1778x over previous
//
#include <hip/hip_runtime.h>

#define DIMS 1024
#define DEXT 1088        // fp8 bytes per row: 1024 data + 64-byte norm-digit tile
#define KNN_K 8
#define BM 128
#define BN 128
#define KT 64
#define NT 17            // DEXT / KT

typedef float f32x4 __attribute__((ext_vector_type(4)));
typedef long long ll;
typedef ll llx2 __attribute__((ext_vector_type(2)));

#define BAR() asm volatile("s_barrier" ::: "memory")
#define CVT(a, b, old, w) __builtin_amdgcn_cvt_pk_fp8_f32((a), (b), (old), (w))

// compare-exchange (ascending)
__device__ __forceinline__ void ce(float& a, float& b) {
  float lo = fminf(a, b), hi = fmaxf(a, b); a = lo; b = hi;
}
// Batcher odd-even merge sort, 8 elements ascending (19 CE, branch-free)
__device__ __forceinline__ void sort8(float (&v)[8]) {
  ce(v[0],v[1]); ce(v[2],v[3]); ce(v[4],v[5]); ce(v[6],v[7]);
  ce(v[0],v[2]); ce(v[1],v[3]); ce(v[4],v[6]); ce(v[5],v[7]);
  ce(v[1],v[2]); ce(v[5],v[6]);
  ce(v[0],v[4]); ce(v[1],v[5]); ce(v[2],v[6]); ce(v[3],v[7]);
  ce(v[2],v[4]); ce(v[3],v[5]);
  ce(v[1],v[2]); ce(v[3],v[4]); ce(v[5],v[6]);
}
// a,b ascending sorted-8 -> a = smallest 8 of union, ascending
__device__ __forceinline__ void merge8(float (&a)[8], const float (&b)[8]) {
  float u[8];
  #pragma unroll
  for (int k = 0; k < 8; ++k) u[k] = fminf(a[k], b[7 - k]);  // bitonic
  ce(u[0],u[4]); ce(u[1],u[5]); ce(u[2],u[6]); ce(u[3],u[7]);
  ce(u[0],u[2]); ce(u[1],u[3]); ce(u[4],u[6]); ce(u[5],u[7]);
  ce(u[0],u[1]); ce(u[2],u[3]); ce(u[4],u[5]); ce(u[6],u[7]);
  #pragma unroll
  for (int k = 0; k < 8; ++k) a[k] = u[k];
}

__device__ __forceinline__ void gload_lds16(const void* g, void* l) {
  __builtin_amdgcn_global_load_lds(
      (const __attribute__((address_space(1))) void*)g,
      (__attribute__((address_space(3))) void*)l, 16, 0, 0);
}

// ---- prep: norms + fp8 convert (k-permuted) + norm-digit bake + out copy ---
// Row layout (bytes, per 64-k tile t): chunk c' (8 k) at t*64+(c'&3)*16+(c'>>2)*8
// => logical 16B slot s = bytes for k'=s*8..+7 (lo) and k'=32+s*8..+7 (hi):
//    exactly one ds_read_b128 feeds both K=32 MFMA slices for lane group g4=s.
// Tile 16: x row: [d1,d2,d3,8,8,8,0...]; y row: [8,8,8,e1,e2,e3,0...], where
// 8*(d1+d2+d3) ~= ||x||^2 (3-digit fp8 split) => MFMA acc = squared distance.
template<bool PRE>
__global__ void prep_kernel(const float* __restrict__ x, const float* __restrict__ y,
                            float* __restrict__ x2, float* __restrict__ y2,
                            char* __restrict__ xb, char* __restrict__ yb,
                            const float4* __restrict__ mind4, float4* __restrict__ out4,
                            int n4, int B, int M, int nNormBlocks) {
  if ((int)blockIdx.x >= nNormBlocks) {        // tail blocks: full-buffer copy
    int i = ((int)blockIdx.x - nNormBlocks) * 256 + threadIdx.x;
    if (i < n4) out4[i] = mind4[i];
    return;
  }
  int wv = threadIdx.x >> 6;
  int lane = threadIdx.x & 63;
  int row = blockIdx.x * 4 + wv;
  const float* src;
  float* dst;
  char* bdst;
  bool isY;
  if (row < M) {
    isY = true;
    src = y + (size_t)row * DIMS; dst = y2 + row; bdst = yb + (size_t)row * DEXT;
  } else {
    int r = row - M;
    if (r >= B) return;
    isY = false;
    src = x + (size_t)r * DIMS; dst = x2 + r; bdst = xb + (size_t)r * DEXT;
  }
  const float g = isY ? -2.f : 1.f;
  float s = 0.f;
  #pragma unroll
  for (int h = 0; h < 2; ++h) {
    int c = h * 64 + lane;                     // chunk of 8 k
    const float4* fp = (const float4*)(src + c * 8);
    float4 a0 = fp[0], a1 = fp[1];
    s = fmaf(a0.x, a0.x, s); s = fmaf(a0.y, a0.y, s);
    s = fmaf(a0.z, a0.z, s); s = fmaf(a0.w, a0.w, s);
    s = fmaf(a1.x, a1.x, s); s = fmaf(a1.y, a1.y, s);
    s = fmaf(a1.z, a1.z, s); s = fmaf(a1.w, a1.w, s);
    if (PRE) {
      int lo = CVT(g * a0.x, g * a0.y, 0, 0); lo = CVT(g * a0.z, g * a0.w, lo, 1);
      int hi = CVT(g * a1.x, g * a1.y, 0, 0); hi = CVT(g * a1.z, g * a1.w, hi, 1);
      int t = c >> 3, cp = c & 7;
      *(int2*)(bdst + t * 64 + (cp & 3) * 16 + (cp >> 2) * 8) = make_int2(lo, hi);
    }
  }
  #pragma unroll
  for (int off = 32; off; off >>= 1) s += __shfl_xor(s, off);
  if (lane == 0) *dst = s;
  if (PRE && lane < 8) {                       // norm-digit tile (k 1024..1087)
    int lo = 0, hi = 0;
    if (lane == 0) {
      float u = s * 0.125f;                    // ~128; 3-digit e4m3 split
      float d1 = rintf(u * 0.0625f) * 16.f;    // ulp 16 grid
      float r1 = u - d1;
      float d2 = rintf(r1);                    // ulp 1 grid
      float d3 = rintf((r1 - d2) * 16.f) * 0.0625f;  // ulp 1/16 grid
      if (!isY) { lo = CVT(d1, d2, 0, 0); lo = CVT(d3, 8.f, lo, 1);
                  hi = CVT(8.f, 8.f, 0, 0); }
      else      { lo = CVT(8.f, 8.f, 0, 0); lo = CVT(8.f, d1, lo, 1);
                  hi = CVT(d2, d3, 0, 0); }
    }
    *(int2*)(bdst + 1024 + (lane & 3) * 16 + (lane >> 2) * 8) = make_int2(lo, hi);
  }
}

// ---------------- phase A: fp8 MFMA 128x128, dbuf counted-vmcnt, 4 blk/CU --
// grid 1024 (rowblk=bid>>6, colchunk=bid&63); 256 thr = 4 waves 2x2, wave 64x64.
// Per tile: 8 ds_read_b128 + 32 mfma_fp8 per wave (half of bf16's LDS bytes).
template<bool PRE>
__global__ __launch_bounds__(256, 4) void knn_fp8(
    const float* __restrict__ xf, const float* __restrict__ yf,
    const char* __restrict__ xb, const char* __restrict__ yb,
    const float* __restrict__ x2, const float* __restrict__ y2,
    float* __restrict__ topk_out,           // [nch][B][8] squared dists
    const int* __restrict__ xsp, const int* __restrict__ ysp,
    int B, int M, int nch) {
  __shared__ __align__(16) char smem[32768]; // 2 x (A 8KB + B 8KB); 4KB reuse
  const int tid = threadIdx.x;
  const int wv = tid >> 6, l = tid & 63;
  const int wr = wv >> 1, wc = wv & 1;
  const int g4 = l >> 4, l16 = l & 15;
  const int rowblk = blockIdx.x >> 6, colchunk = blockIdx.x & 63;
  const int r0 = rowblk * BM, c0 = colchunk * BN;
  const int xs = *xsp, ys = *ysp;
  const float FINF = __builtin_inff();

  f32x4 acc[4][4];
  #pragma unroll
  for (int mi = 0; mi < 4; ++mi)
    #pragma unroll
    for (int ni = 0; ni < 4; ++ni)
      acc[mi][ni] = (f32x4){0.f, 0.f, 0.f, 0.f};

  auto STAGE = [&](char* buf, int t) {       // A 8KB then B 8KB; 4 gload/thread
    #pragma unroll
    for (int p = 0; p < 2; ++p) {
      int row = p * 64 + (tid >> 2);
      int ls = (tid & 3) ^ ((row >> 1) & 3); // pre-swizzled logical slot
      gload_lds16(xb + (size_t)(r0 + row) * DEXT + t * KT + ls * 16,
                  buf + p * 4096 + tid * 16);
    }
    #pragma unroll
    for (int p = 0; p < 2; ++p) {
      int row = p * 64 + (tid >> 2);
      int ls = (tid & 3) ^ ((row >> 1) & 3);
      gload_lds16(yb + (size_t)(c0 + row) * DEXT + t * KT + ls * 16,
                  buf + 8192 + p * 4096 + tid * 16);
    }
  };
  auto STAGE_CONV = [&](char* buf, int t) {  // fallback: f32 -> fp8 in-reg
    #pragma unroll
    for (int p = 0; p < 2; ++p) {
      int row = p * 64 + (tid >> 2);
      int ph = tid & 3;
      int ls = ph ^ ((row >> 1) & 3);
      {
        const float* g0 = xf + (size_t)(r0 + row) * DIMS + t * KT + ls * 8;
        float4 a0 = *(const float4*)g0, a1 = *(const float4*)(g0 + 4);
        float4 b0 = *(const float4*)(g0 + 32), b1 = *(const float4*)(g0 + 36);
        int w0 = CVT(a0.x, a0.y, 0, 0); w0 = CVT(a0.z, a0.w, w0, 1);
        int w1 = CVT(a1.x, a1.y, 0, 0); w1 = CVT(a1.z, a1.w, w1, 1);
        int w2 = CVT(b0.x, b0.y, 0, 0); w2 = CVT(b0.z, b0.w, w2, 1);
        int w3 = CVT(b1.x, b1.y, 0, 0); w3 = CVT(b1.z, b1.w, w3, 1);
        *(int4*)(buf + row * 64 + ph * 16) = make_int4(w0, w1, w2, w3);
      }
      {
        const float* g0 = yf + (size_t)(c0 + row) * DIMS + t * KT + ls * 8;
        float4 a0 = *(const float4*)g0, a1 = *(const float4*)(g0 + 4);
        float4 b0 = *(const float4*)(g0 + 32), b1 = *(const float4*)(g0 + 36);
        int w0 = CVT(-2.f*a0.x, -2.f*a0.y, 0, 0); w0 = CVT(-2.f*a0.z, -2.f*a0.w, w0, 1);
        int w1 = CVT(-2.f*a1.x, -2.f*a1.y, 0, 0); w1 = CVT(-2.f*a1.z, -2.f*a1.w, w1, 1);
        int w2 = CVT(-2.f*b0.x, -2.f*b0.y, 0, 0); w2 = CVT(-2.f*b0.z, -2.f*b0.w, w2, 1);
        int w3 = CVT(-2.f*b1.x, -2.f*b1.y, 0, 0); w3 = CVT(-2.f*b1.z, -2.f*b1.w, w3, 1);
        *(int4*)(buf + 8192 + row * 64 + ph * 16) = make_int4(w0, w1, w2, w3);
      }
    }
  };

  llx2 af[4], bf[4];
  auto LOADF = [&](const char* buf) {        // 8 ds_read_b128 per wave
    #pragma unroll
    for (int mi = 0; mi < 4; ++mi) {
      int row = wr * 64 + mi * 16 + l16;
      af[mi] = *(const llx2*)(buf + row * 64 + ((g4 ^ ((row >> 1) & 3)) * 16));
    }
    #pragma unroll
    for (int ni = 0; ni < 4; ++ni) {
      int col = wc * 64 + ni * 16 + l16;
      bf[ni] = *(const llx2*)(buf + 8192 + col * 64 + ((g4 ^ ((col >> 1) & 3)) * 16));
    }
  };
  auto FMA = [&]() {                          // swapped operands: C[ycol][xrow]
    #pragma unroll
    for (int mi = 0; mi < 4; ++mi)
      #pragma unroll
      for (int ni = 0; ni < 4; ++ni) {
        acc[mi][ni] = __builtin_amdgcn_mfma_f32_16x16x32_fp8_fp8(
            bf[ni].x, af[mi].x, acc[mi][ni], 0, 0, 0);
        acc[mi][ni] = __builtin_amdgcn_mfma_f32_16x16x32_fp8_fp8(
            bf[ni].y, af[mi].y, acc[mi][ni], 0, 0, 0);
      }
  };

  if (PRE) {
    STAGE(smem, 0);                           // prologue: tile 0 in flight
    #pragma unroll 1
    for (int t = 0; t < NT; ++t) {
      char* cb = smem + (t & 1) * 16384;
      char* nb = smem + ((t + 1) & 1) * 16384;
      if (t + 1 < NT) {
        STAGE(nb, t + 1);                     // 4 loads -> other buffer
        asm volatile("s_waitcnt vmcnt(4)" ::: "memory");  // tile t landed only
      } else {
        asm volatile("s_waitcnt vmcnt(0)" ::: "memory");
      }
      BAR();                                  // tile t visible to all waves
      LOADF(cb);
      FMA();
      BAR();                                  // all waves done reading tile t
    }
  } else {
    #pragma unroll 1
    for (int t = 0; t < DIMS / KT; ++t) {
      __syncthreads();
      STAGE_CONV(smem, t);
      __syncthreads();
      LOADF(smem);
      FMA();
    }
  }

  // ---- epilogue: per-lane in-register top-8 (r11-verified structure) ------
  const int cb2 = c0 + wc * 64 + g4 * 4;
  float y2v[16];
  if (!PRE) {
    #pragma unroll
    for (int ni = 0; ni < 4; ++ni)
      #pragma unroll
      for (int j = 0; j < 4; ++j)
        y2v[ni * 4 + j] = y2[cb2 + ni * 16 + j];
  }

  float t8[4][8];
  #pragma unroll
  for (int mi = 0; mi < 4; ++mi) {
    const int gr = r0 + wr * 64 + mi * 16 + l16;
    const int dmi = xs + gr - ys - cb2;       // equals ni*16+j iff self-pair
    const float xv = PRE ? 0.f : x2[gr];
    float a[8], b[8];
    #pragma unroll
    for (int ni = 0; ni < 2; ++ni)
      #pragma unroll
      for (int j = 0; j < 4; ++j) {
        float sq = PRE ? fmaxf(acc[mi][ni][j], 0.f)
                       : fmaxf(xv + y2v[ni * 4 + j] - 2.f * acc[mi][ni][j], 0.f);
        if (dmi == ni * 16 + j) sq = FINF;
        a[ni * 4 + j] = sq;
      }
    #pragma unroll
    for (int ni = 2; ni < 4; ++ni)
      #pragma unroll
      for (int j = 0; j < 4; ++j) {
        float sq = PRE ? fmaxf(acc[mi][ni][j], 0.f)
                       : fmaxf(xv + y2v[ni * 4 + j] - 2.f * acc[mi][ni][j], 0.f);
        if (dmi == ni * 16 + j) sq = FINF;
        b[(ni - 2) * 4 + j] = sq;
      }
    sort8(a); sort8(b); merge8(a, b);         // top8 of lane's 16, ascending
    #pragma unroll
    for (int k = 0; k < 8; ++k) b[k] = __shfl_xor(a[k], 16);
    merge8(a, b);
    #pragma unroll
    for (int k = 0; k < 8; ++k) b[k] = __shfl_xor(a[k], 32);
    merge8(a, b);                             // all 4 g4 groups merged
    #pragma unroll
    for (int k = 0; k < 8; ++k) t8[mi][k] = a[k];
  }

  float* xbuf = (float*)smem;                 // 4KB hop to merge wc strips
  __syncthreads();
  if (wc == 1 && g4 == 0) {
    #pragma unroll
    for (int mi = 0; mi < 4; ++mi) {
      float* p = xbuf + ((wr * 4 + mi) * 16 + l16) * 8;
      *(f32x4*)p       = (f32x4){t8[mi][0], t8[mi][1], t8[mi][2], t8[mi][3]};
      *((f32x4*)p + 1) = (f32x4){t8[mi][4], t8[mi][5], t8[mi][6], t8[mi][7]};
    }
  }
  __syncthreads();
  if (wc == 0 && g4 == 0) {
    #pragma unroll
    for (int mi = 0; mi < 4; ++mi) {
      const float* p = xbuf + ((wr * 4 + mi) * 16 + l16) * 8;
      float b[8];
      #pragma unroll
      for (int k = 0; k < 8; ++k) b[k] = p[k];
      merge8(t8[mi], b);
      int gr = r0 + wr * 64 + mi * 16 + l16;
      float* o = topk_out + ((size_t)colchunk * B + gr) * 8;
      *(f32x4*)o       = (f32x4){t8[mi][0], t8[mi][1], t8[mi][2], t8[mi][3]};
      *((f32x4*)o + 1) = (f32x4){t8[mi][4], t8[mi][5], t8[mi][6], t8[mi][7]};
    }
  }
}

// ---------------- phase B: wave-per-row merge of nch sorted lists ----------
__global__ void knn_phaseB(const float* __restrict__ topk,
                           const float* __restrict__ mind_in,
                           float* __restrict__ out,
                           const int* __restrict__ xsp, int B, int nch) {
  int w = threadIdx.x >> 6, lane = threadIdx.x & 63;
  int r = blockIdx.x * 4 + w;
  if (r >= B) return;
  int x_start = *xsp;
  const float* bp = topk + ((size_t)lane * B + r) * 8;   // chunk = lane (nch=64)
  float t8[8];
  f32x4 v0 = *(const f32x4*)bp;
  f32x4 v1 = *(const f32x4*)(bp + 4);
  t8[0]=v0[0]; t8[1]=v0[1]; t8[2]=v0[2]; t8[3]=v0[3];
  t8[4]=v1[0]; t8[5]=v1[1]; t8[6]=v1[2]; t8[7]=v1[3];
  #pragma unroll
  for (int off = 32; off >= 1; off >>= 1) {              // butterfly merge
    float b[8];
    #pragma unroll
    for (int k = 0; k < 8; ++k) b[k] = __shfl_xor(t8[k], off);
    merge8(t8, b);
  }
  if (lane == 0) {
    float lst[8];
    #pragma unroll
    for (int k = 0; k < 8; ++k) lst[k] = sqrtf(t8[k]);   // squared -> distance
    float cur[8];
    const float* cp = mind_in + (size_t)(x_start + r) * KNN_K;
    #pragma unroll
    for (int k = 0; k < 8; ++k) cur[k] = cp[k];
    sort8(cur);
    merge8(lst, cur);
    #pragma unroll
    for (int k = 0; k < 8; ++k) out[(size_t)(x_start + r) * KNN_K + k] = lst[k];
  }
}

extern "C" void kernel_launch(void* const* d_in, const int* in_sizes, int n_in,
                              void* d_out, int out_size, void* d_ws, size_t ws_size,
                              hipStream_t stream) {
  const float* x = (const float*)d_in[0];
  const float* y = (const float*)d_in[1];
  const float* mind = (const float*)d_in[2];
  const int* xsp = (const int*)d_in[3];
  const int* ysp = (const int*)d_in[4];
  float* out = (float*)d_out;

  const int B = in_sizes[0] / DIMS;       // 2048
  const int M = in_sizes[1] / DIMS;       // 8192
  const int nch = M / BN;                 // 64

  float* y2 = (float*)d_ws;               // [M]
  float* x2 = y2 + M;                     // [B]
  float* topk = x2 + B;                   // [nch][B][8]
  size_t base = ((size_t)(M + B) + (size_t)B * nch * 8) * 4;
  base = (base + 255) & ~(size_t)255;
  char* xbw = (char*)d_ws + base;
  char* ybw = xbw + (size_t)B * DEXT;
  size_t need = base + ((size_t)B + (size_t)M) * DEXT;
  bool pre = ws_size >= need;

  int nNorm = (B + M + 3) / 4;
  int n4 = out_size / 4;
  int nCopy = (n4 + 255) / 256;
  if (pre)
    prep_kernel<true><<<nNorm + nCopy, 256, 0, stream>>>(
        x, y, x2, y2, xbw, ybw, (const float4*)mind, (float4*)out, n4, B, M, nNorm);
  else
    prep_kernel<false><<<nNorm + nCopy, 256, 0, stream>>>(
        x, y, x2, y2, xbw, ybw, (const float4*)mind, (float4*)out, n4, B, M, nNorm);

  int nBlocks = (B / BM) * nch;           // 16 x 64 = 1024 (4 blocks/CU)
  if (pre)
    knn_fp8<true><<<nBlocks, 256, 0, stream>>>(x, y, xbw, ybw, x2, y2, topk, xsp, ysp, B, M, nch);
  else
    knn_fp8<false><<<nBlocks, 256, 0, stream>>>(x, y, xbw, ybw, x2, y2, topk, xsp, ysp, B, M, nch);

  knn_phaseB<<<(B + 3) / 4, 256, 0, stream>>>(topk, mind, out, xsp, B, nch);
}

// Round 13
// 47.373 us; speedup vs baseline: 2.8240x; 1.1279x over previous
//
#include <hip/hip_runtime.h>

#define DIMS 1024
#define DEXT 1152        // fp8 bytes per row: 1024 data + 128-byte norm-digit tile
#define KNN_K 8
#define BM 128
#define BN 128
#define KT 128
#define NT 9             // DEXT / KT (PRE path)

typedef float f32x4 __attribute__((ext_vector_type(4)));
typedef int i32x4 __attribute__((ext_vector_type(4)));
typedef int i32x8 __attribute__((ext_vector_type(8)));

#define CVT(a, b, old, w) __builtin_amdgcn_cvt_pk_fp8_f32((a), (b), (old), (w))
#define SCL 0x7f7f7f7f   // E8M0 = 127 -> x1 block scale

// compare-exchange (ascending)
__device__ __forceinline__ void ce(float& a, float& b) {
  float lo = fminf(a, b), hi = fmaxf(a, b); a = lo; b = hi;
}
// Batcher odd-even merge sort, 8 elements ascending (19 CE, branch-free)
__device__ __forceinline__ void sort8(float (&v)[8]) {
  ce(v[0],v[1]); ce(v[2],v[3]); ce(v[4],v[5]); ce(v[6],v[7]);
  ce(v[0],v[2]); ce(v[1],v[3]); ce(v[4],v[6]); ce(v[5],v[7]);
  ce(v[1],v[2]); ce(v[5],v[6]);
  ce(v[0],v[4]); ce(v[1],v[5]); ce(v[2],v[6]); ce(v[3],v[7]);
  ce(v[2],v[4]); ce(v[3],v[5]);
  ce(v[1],v[2]); ce(v[3],v[4]); ce(v[5],v[6]);
}
// a,b ascending sorted-8 -> a = smallest 8 of union, ascending
__device__ __forceinline__ void merge8(float (&a)[8], const float (&b)[8]) {
  float u[8];
  #pragma unroll
  for (int k = 0; k < 8; ++k) u[k] = fminf(a[k], b[7 - k]);  // bitonic
  ce(u[0],u[4]); ce(u[1],u[5]); ce(u[2],u[6]); ce(u[3],u[7]);
  ce(u[0],u[2]); ce(u[1],u[3]); ce(u[4],u[6]); ce(u[5],u[7]);
  ce(u[0],u[1]); ce(u[2],u[3]); ce(u[4],u[5]); ce(u[6],u[7]);
  #pragma unroll
  for (int k = 0; k < 8; ++k) a[k] = u[k];
}

__device__ __forceinline__ void gload_lds16(const void* g, void* l) {
  __builtin_amdgcn_global_load_lds(
      (const __attribute__((address_space(1))) void*)g,
      (__attribute__((address_space(3))) void*)l, 16, 0, 0);
}

// ---- prep: norms + fp8 convert (linear k) + norm-digit bake + out copy ----
// x rows -> xb[0..1023]=fp8(x);    bytes 1024..: [d1,d2,d3,8,8,8,0...]
// y rows -> yb[0..1023]=fp8(-2y);  bytes 1024..: [8,8,8,e1,e2,e3,0...]
// 8*(d1+d2+d3) ~= ||x||^2 (3-digit e4m3, grid 1/32*8=0.25 max err)
// => MX MFMA dot over 1152 = x2 + y2 - 2 x.y  (squared distance, direct)
template<bool PRE>
__global__ void prep_kernel(const float* __restrict__ x, const float* __restrict__ y,
                            float* __restrict__ x2, float* __restrict__ y2,
                            char* __restrict__ xb, char* __restrict__ yb,
                            const float4* __restrict__ mind4, float4* __restrict__ out4,
                            int n4, int B, int M, int nNormBlocks) {
  if ((int)blockIdx.x >= nNormBlocks) {        // tail blocks: full-buffer copy
    int i = ((int)blockIdx.x - nNormBlocks) * 256 + threadIdx.x;
    if (i < n4) out4[i] = mind4[i];
    return;
  }
  int wv = threadIdx.x >> 6;
  int lane = threadIdx.x & 63;
  int row = blockIdx.x * 4 + wv;
  const float* src;
  float* dst;
  char* bdst;
  bool isY;
  if (row < M) {
    isY = true;
    src = y + (size_t)row * DIMS; dst = y2 + row; bdst = yb + (size_t)row * DEXT;
  } else {
    int r = row - M;
    if (r >= B) return;
    isY = false;
    src = x + (size_t)r * DIMS; dst = x2 + r; bdst = xb + (size_t)r * DEXT;
  }
  const float g = isY ? -2.f : 1.f;
  float s = 0.f;
  #pragma unroll
  for (int h = 0; h < 2; ++h) {
    int c = h * 64 + lane;                     // chunk of 8 k
    const float4* fp = (const float4*)(src + c * 8);
    float4 a0 = fp[0], a1 = fp[1];
    s = fmaf(a0.x, a0.x, s); s = fmaf(a0.y, a0.y, s);
    s = fmaf(a0.z, a0.z, s); s = fmaf(a0.w, a0.w, s);
    s = fmaf(a1.x, a1.x, s); s = fmaf(a1.y, a1.y, s);
    s = fmaf(a1.z, a1.z, s); s = fmaf(a1.w, a1.w, s);
    if (PRE) {
      int lo = CVT(g * a0.x, g * a0.y, 0, 0); lo = CVT(g * a0.z, g * a0.w, lo, 1);
      int hi = CVT(g * a1.x, g * a1.y, 0, 0); hi = CVT(g * a1.z, g * a1.w, hi, 1);
      *(int2*)(bdst + c * 8) = make_int2(lo, hi);   // linear k layout
    }
  }
  #pragma unroll
  for (int off = 32; off; off >>= 1) s += __shfl_xor(s, off);
  if (lane == 0) *dst = s;
  if (PRE && lane < 16) {                      // norm-digit tile (k 1024..1151)
    if (lane == 0) {
      float u = s * 0.125f;                    // ~128; 3-digit e4m3 split
      float d1 = rintf(u * 0.0625f) * 16.f;    // ulp-16 grid
      float r1 = u - d1;
      float d2 = rintf(r1);                    // ulp-1 grid
      float d3 = rintf((r1 - d2) * 16.f) * 0.0625f;  // ulp-1/16 grid
      int w0, w1;
      if (!isY) { w0 = CVT(d1, d2, 0, 0); w0 = CVT(d3, 8.f, w0, 1);
                  w1 = CVT(8.f, 8.f, 0, 0); }
      else      { w0 = CVT(8.f, 8.f, 0, 0); w0 = CVT(8.f, d1, w0, 1);
                  w1 = CVT(d2, d3, 0, 0); }
      *(int2*)(bdst + 1024) = make_int2(w0, w1);
    } else {
      *(int2*)(bdst + 1024 + lane * 8) = make_int2(0, 0);
    }
  }
}

// ---------------- phase A: MX-fp8 K=128 MFMA 128x128, 4 blocks/CU ----------
// grid 1024 (rowblk=bid>>6, colchunk=bid&63); 256 thr = 4 waves 2x2, wave 64x64.
// Single 32KB LDS buffer, 2 syncthreads/tile (m97 structure; cross-block
// overlap hides the drain). Per tile/wave: 16 ds_read_b128 + 16 K=128 MFMA.
template<bool PRE>
__global__ __launch_bounds__(256, 4) void knn_mx(
    const float* __restrict__ xf, const float* __restrict__ yf,
    const char* __restrict__ xb, const char* __restrict__ yb,
    const float* __restrict__ x2, const float* __restrict__ y2,
    float* __restrict__ topk_out,           // [nch][B][8] squared dists
    const int* __restrict__ xsp, const int* __restrict__ ysp,
    int B, int M, int nch) {
  __shared__ __align__(16) char smem[32768]; // A 16KB + B 16KB; 4KB reuse at end
  const int tid = threadIdx.x;
  const int wv = tid >> 6, l = tid & 63;
  const int wr = wv >> 1, wc = wv & 1;
  const int g4 = l >> 4, l16 = l & 15;
  const int rowblk = blockIdx.x >> 6, colchunk = blockIdx.x & 63;
  const int r0 = rowblk * BM, c0 = colchunk * BN;
  const int xs = *xsp, ys = *ysp;
  const float FINF = __builtin_inff();

  f32x4 acc[4][4];
  #pragma unroll
  for (int mi = 0; mi < 4; ++mi)
    #pragma unroll
    for (int ni = 0; ni < 4; ++ni)
      acc[mi][ni] = (f32x4){0.f, 0.f, 0.f, 0.f};

  // stage: rows [128][128B] linear-k, slot-swizzled (phys slot = s ^ (row&7))
  auto STAGE = [&](int t) {
    #pragma unroll
    for (int p = 0; p < 4; ++p) {
      int row = p * 32 + (tid >> 3);
      int s = (tid & 7) ^ (row & 7);           // pre-inverse-swizzled source
      gload_lds16(xb + (size_t)(r0 + row) * DEXT + t * KT + s * 16,
                  smem + p * 4096 + tid * 16);
    }
    #pragma unroll
    for (int p = 0; p < 4; ++p) {
      int row = p * 32 + (tid >> 3);
      int s = (tid & 7) ^ (row & 7);
      gload_lds16(yb + (size_t)(c0 + row) * DEXT + t * KT + s * 16,
                  smem + 16384 + p * 4096 + tid * 16);
    }
  };
  auto STAGE_CONV = [&](int t) {               // fallback: f32 -> fp8 in-reg
    #pragma unroll
    for (int p = 0; p < 4; ++p) {
      int row = p * 32 + (tid >> 3);
      int s = (tid & 7) ^ (row & 7);
      {
        const float* g0 = xf + (size_t)(r0 + row) * DIMS + t * KT + s * 16;
        float4 a0 = *(const float4*)g0, a1 = *(const float4*)(g0 + 4);
        float4 a2 = *(const float4*)(g0 + 8), a3 = *(const float4*)(g0 + 12);
        int w0 = CVT(a0.x, a0.y, 0, 0); w0 = CVT(a0.z, a0.w, w0, 1);
        int w1 = CVT(a1.x, a1.y, 0, 0); w1 = CVT(a1.z, a1.w, w1, 1);
        int w2 = CVT(a2.x, a2.y, 0, 0); w2 = CVT(a2.z, a2.w, w2, 1);
        int w3 = CVT(a3.x, a3.y, 0, 0); w3 = CVT(a3.z, a3.w, w3, 1);
        *(int4*)(smem + p * 4096 + tid * 16) = make_int4(w0, w1, w2, w3);
      }
      {
        const float* g0 = yf + (size_t)(c0 + row) * DIMS + t * KT + s * 16;
        float4 a0 = *(const float4*)g0, a1 = *(const float4*)(g0 + 4);
        float4 a2 = *(const float4*)(g0 + 8), a3 = *(const float4*)(g0 + 12);
        int w0 = CVT(a0.x, a0.y, 0, 0); w0 = CVT(a0.z, a0.w, w0, 1);
        int w1 = CVT(a1.x, a1.y, 0, 0); w1 = CVT(a1.z, a1.w, w1, 1);
        int w2 = CVT(a2.x, a2.y, 0, 0); w2 = CVT(a2.z, a2.w, w2, 1);
        int w3 = CVT(a3.x, a3.y, 0, 0); w3 = CVT(a3.z, a3.w, w3, 1);
        *(int4*)(smem + 16384 + p * 4096 + tid * 16) = make_int4(w0, w1, w2, w3);
      }
    }
  };

  auto LDFRAG = [&](const char* base, int row) -> i32x8 {
    i32x4 lo = *(const i32x4*)(base + row * 128 + (((g4 * 2 + 0) ^ (row & 7)) * 16));
    i32x4 hi = *(const i32x4*)(base + row * 128 + (((g4 * 2 + 1) ^ (row & 7)) * 16));
    i32x8 v;
    v[0] = lo[0]; v[1] = lo[1]; v[2] = lo[2]; v[3] = lo[3];
    v[4] = hi[0]; v[5] = hi[1]; v[6] = hi[2]; v[7] = hi[3];
    return v;
  };

  auto COMPUTE = [&]() {
    i32x8 bf[4];
    #pragma unroll
    for (int ni = 0; ni < 4; ++ni)
      bf[ni] = LDFRAG(smem + 16384, wc * 64 + ni * 16 + l16);
    #pragma unroll
    for (int mi = 0; mi < 4; ++mi) {
      i32x8 a = LDFRAG(smem, wr * 64 + mi * 16 + l16);
      #pragma unroll
      for (int ni = 0; ni < 4; ++ni)
        acc[mi][ni] = __builtin_amdgcn_mfma_scale_f32_16x16x128_f8f6f4(
            bf[ni], a, acc[mi][ni], 0, 0, 0, SCL, 0, SCL);  // swapped: C[ycol][xrow]
    }
  };

  if (PRE) {
    #pragma unroll 1
    for (int t = 0; t < NT; ++t) {
      __syncthreads();                         // prev tile's readers done
      STAGE(t);
      __syncthreads();                         // tile staged (vmcnt drained)
      COMPUTE();
    }
  } else {
    #pragma unroll 1
    for (int t = 0; t < DIMS / KT; ++t) {
      __syncthreads();
      STAGE_CONV(t);
      __syncthreads();
      COMPUTE();
    }
  }

  // ---- epilogue: per-lane in-register top-8 (r11/r12-verified structure) --
  const int cb2 = c0 + wc * 64 + g4 * 4;
  float y2v[16];
  if (!PRE) {
    #pragma unroll
    for (int ni = 0; ni < 4; ++ni)
      #pragma unroll
      for (int j = 0; j < 4; ++j)
        y2v[ni * 4 + j] = y2[cb2 + ni * 16 + j];
  }

  float t8[4][8];
  #pragma unroll
  for (int mi = 0; mi < 4; ++mi) {
    const int gr = r0 + wr * 64 + mi * 16 + l16;
    const int dmi = xs + gr - ys - cb2;        // equals ni*16+j iff self-pair
    const float xv = PRE ? 0.f : x2[gr];
    float a[8], b[8];
    #pragma unroll
    for (int ni = 0; ni < 2; ++ni)
      #pragma unroll
      for (int j = 0; j < 4; ++j) {
        float sq = PRE ? fmaxf(acc[mi][ni][j], 0.f)
                       : fmaxf(xv + y2v[ni * 4 + j] - 2.f * acc[mi][ni][j], 0.f);
        if (dmi == ni * 16 + j) sq = FINF;
        a[ni * 4 + j] = sq;
      }
    #pragma unroll
    for (int ni = 2; ni < 4; ++ni)
      #pragma unroll
      for (int j = 0; j < 4; ++j) {
        float sq = PRE ? fmaxf(acc[mi][ni][j], 0.f)
                       : fmaxf(xv + y2v[ni * 4 + j] - 2.f * acc[mi][ni][j], 0.f);
        if (dmi == ni * 16 + j) sq = FINF;
        b[(ni - 2) * 4 + j] = sq;
      }
    sort8(a); sort8(b); merge8(a, b);          // top8 of lane's 16, ascending
    #pragma unroll
    for (int k = 0; k < 8; ++k) b[k] = __shfl_xor(a[k], 16);
    merge8(a, b);
    #pragma unroll
    for (int k = 0; k < 8; ++k) b[k] = __shfl_xor(a[k], 32);
    merge8(a, b);                              // all 4 g4 groups merged
    #pragma unroll
    for (int k = 0; k < 8; ++k) t8[mi][k] = a[k];
  }

  float* xbuf = (float*)smem;                  // 4KB hop to merge wc strips
  __syncthreads();
  if (wc == 1 && g4 == 0) {
    #pragma unroll
    for (int mi = 0; mi < 4; ++mi) {
      float* p = xbuf + ((wr * 4 + mi) * 16 + l16) * 8;
      *(f32x4*)p       = (f32x4){t8[mi][0], t8[mi][1], t8[mi][2], t8[mi][3]};
      *((f32x4*)p + 1) = (f32x4){t8[mi][4], t8[mi][5], t8[mi][6], t8[mi][7]};
    }
  }
  __syncthreads();
  if (wc == 0 && g4 == 0) {
    #pragma unroll
    for (int mi = 0; mi < 4; ++mi) {
      const float* p = xbuf + ((wr * 4 + mi) * 16 + l16) * 8;
      float b[8];
      #pragma unroll
      for (int k = 0; k < 8; ++k) b[k] = p[k];
      merge8(t8[mi], b);
      int gr = r0 + wr * 64 + mi * 16 + l16;
      float* o = topk_out + ((size_t)colchunk * B + gr) * 8;
      *(f32x4*)o       = (f32x4){t8[mi][0], t8[mi][1], t8[mi][2], t8[mi][3]};
      *((f32x4*)o + 1) = (f32x4){t8[mi][4], t8[mi][5], t8[mi][6], t8[mi][7]};
    }
  }
}

// ---------------- phase B: wave-per-row merge of nch sorted lists ----------
__global__ void knn_phaseB(const float* __restrict__ topk,
                           const float* __restrict__ mind_in,
                           float* __restrict__ out,
                           const int* __restrict__ xsp, int B, int nch) {
  int w = threadIdx.x >> 6, lane = threadIdx.x & 63;
  int r = blockIdx.x * 4 + w;
  if (r >= B) return;
  int x_start = *xsp;
  const float* bp = topk + ((size_t)lane * B + r) * 8;   // chunk = lane (nch=64)
  float t8[8];
  f32x4 v0 = *(const f32x4*)bp;
  f32x4 v1 = *(const f32x4*)(bp + 4);
  t8[0]=v0[0]; t8[1]=v0[1]; t8[2]=v0[2]; t8[3]=v0[3];
  t8[4]=v1[0]; t8[5]=v1[1]; t8[6]=v1[2]; t8[7]=v1[3];
  #pragma unroll
  for (int off = 32; off >= 1; off >>= 1) {              // butterfly merge
    float b[8];
    #pragma unroll
    for (int k = 0; k < 8; ++k) b[k] = __shfl_xor(t8[k], off);
    merge8(t8, b);
  }
  if (lane == 0) {
    float lst[8];
    #pragma unroll
    for (int k = 0; k < 8; ++k) lst[k] = sqrtf(t8[k]);   // squared -> distance
    float cur[8];
    const float* cp = mind_in + (size_t)(x_start + r) * KNN_K;
    #pragma unroll
    for (int k = 0; k < 8; ++k) cur[k] = cp[k];
    sort8(cur);
    merge8(lst, cur);
    #pragma unroll
    for (int k = 0; k < 8; ++k) out[(size_t)(x_start + r) * KNN_K + k] = lst[k];
  }
}

extern "C" void kernel_launch(void* const* d_in, const int* in_sizes, int n_in,
                              void* d_out, int out_size, void* d_ws, size_t ws_size,
                              hipStream_t stream) {
  const float* x = (const float*)d_in[0];
  const float* y = (const float*)d_in[1];
  const float* mind = (const float*)d_in[2];
  const int* xsp = (const int*)d_in[3];
  const int* ysp = (const int*)d_in[4];
  float* out = (float*)d_out;

  const int B = in_sizes[0] / DIMS;       // 2048
  const int M = in_sizes[1] / DIMS;       // 8192
  const int nch = M / BN;                 // 64

  float* y2 = (float*)d_ws;               // [M]
  float* x2 = y2 + M;                     // [B]
  float* topk = x2 + B;                   // [nch][B][8]
  size_t base = ((size_t)(M + B) + (size_t)B * nch * 8) * 4;
  base = (base + 255) & ~(size_t)255;
  char* xbw = (char*)d_ws + base;
  char* ybw = xbw + (size_t)B * DEXT;
  size_t need = base + ((size_t)B + (size_t)M) * DEXT;
  bool pre = ws_size >= need;

  int nNorm = (B + M + 3) / 4;
  int n4 = out_size / 4;
  int nCopy = (n4 + 255) / 256;
  if (pre)
    prep_kernel<true><<<nNorm + nCopy, 256, 0, stream>>>(
        x, y, x2, y2, xbw, ybw, (const float4*)mind, (float4*)out, n4, B, M, nNorm);
  else
    prep_kernel<false><<<nNorm + nCopy, 256, 0, stream>>>(
        x, y, x2, y2, xbw, ybw, (const float4*)mind, (float4*)out, n4, B, M, nNorm);

  int nBlocks = (B / BM) * nch;           // 16 x 64 = 1024 (4 blocks/CU)
  if (pre)
    knn_mx<true><<<nBlocks, 256, 0, stream>>>(x, y, xbw, ybw, x2, y2, topk, xsp, ysp, B, M, nch);
  else
    knn_mx<false><<<nBlocks, 256, 0, stream>>>(x, y, xbw, ybw, x2, y2, topk, xsp, ysp, B, M, nch);

  knn_phaseB<<<(B + 3) / 4, 256, 0, stream>>>(topk, mind, out, xsp, B, nch);
}

// Round 14
// 43.534 us; speedup vs baseline: 3.0730x; 1.0882x over previous
//
#include <hip/hip_runtime.h>

#define DIMS 1024
#define DEXT 640         // bytes/row: 512 fp4 data + 128 fp8 norm-digit tile
#define KNN_K 8
#define BM 128
#define BN 128

typedef float f32x4 __attribute__((ext_vector_type(4)));
typedef int i32x4 __attribute__((ext_vector_type(4)));
typedef int i32x8 __attribute__((ext_vector_type(8)));

#define CVT(a, b, old, w) __builtin_amdgcn_cvt_pk_fp8_f32((a), (b), (old), (w))
#define SCL1 0x7f7f7f7f  // E8M0 127 -> x1
#define SCL2 0x80808080  // E8M0 128 -> x2 (folds the -2 into -y's scale)

// compare-exchange (ascending)
__device__ __forceinline__ void ce(float& a, float& b) {
  float lo = fminf(a, b), hi = fmaxf(a, b); a = lo; b = hi;
}
// Batcher odd-even merge sort, 8 elements ascending (19 CE, branch-free)
__device__ __forceinline__ void sort8(float (&v)[8]) {
  ce(v[0],v[1]); ce(v[2],v[3]); ce(v[4],v[5]); ce(v[6],v[7]);
  ce(v[0],v[2]); ce(v[1],v[3]); ce(v[4],v[6]); ce(v[5],v[7]);
  ce(v[1],v[2]); ce(v[5],v[6]);
  ce(v[0],v[4]); ce(v[1],v[5]); ce(v[2],v[6]); ce(v[3],v[7]);
  ce(v[2],v[4]); ce(v[3],v[5]);
  ce(v[1],v[2]); ce(v[3],v[4]); ce(v[5],v[6]);
}
// a,b ascending sorted-8 -> a = smallest 8 of union, ascending
__device__ __forceinline__ void merge8(float (&a)[8], const float (&b)[8]) {
  float u[8];
  #pragma unroll
  for (int k = 0; k < 8; ++k) u[k] = fminf(a[k], b[7 - k]);  // bitonic
  ce(u[0],u[4]); ce(u[1],u[5]); ce(u[2],u[6]); ce(u[3],u[7]);
  ce(u[0],u[2]); ce(u[1],u[3]); ce(u[4],u[6]); ce(u[5],u[7]);
  ce(u[0],u[1]); ce(u[2],u[3]); ce(u[4],u[5]); ce(u[6],u[7]);
  #pragma unroll
  for (int k = 0; k < 8; ++k) a[k] = u[k];
}

__device__ __forceinline__ void gload_lds16(const void* g, void* l) {
  __builtin_amdgcn_global_load_lds(
      (const __attribute__((address_space(1))) void*)g,
      (__attribute__((address_space(3))) void*)l, 16, 0, 0);
}

// e2m1 quantize (round-to-nearest): {0,.5,1,1.5,2,3,4,6} + sign
__device__ __forceinline__ unsigned q4(float v) {
  float a = fabsf(v);
  unsigned code = (a >= 0.25f) + (a >= 0.75f) + (a >= 1.25f) + (a >= 1.75f)
                + (a >= 2.5f) + (a >= 3.5f) + (a >= 5.f);
  return (v < 0.f ? 8u : 0u) | code;
}

// ---- prep: norms + fp4 pack (x, -y) + fp8 norm-digit tile + out copy ------
// bytes 0..511: fp4 data (x or -y); bytes 512..639: fp8 norm tile
// x: [d1,d2,d3,8,8,8,0...]; y: [8,8,8,e1,e2,e3,0...]; 8*(d1+d2+d3)~=||x||^2.
// Data MFMA uses scale 2 on the (-y) operand => acc = -2x.y; norm tile (fp8,
// unit scales) adds x2+y2 => acc = squared distance.
template<bool PRE>
__global__ void prep_kernel(const float* __restrict__ x, const float* __restrict__ y,
                            float* __restrict__ x2, float* __restrict__ y2,
                            char* __restrict__ xb, char* __restrict__ yb,
                            const float4* __restrict__ mind4, float4* __restrict__ out4,
                            int n4, int B, int M, int nNormBlocks) {
  if ((int)blockIdx.x >= nNormBlocks) {        // tail blocks: full-buffer copy
    int i = ((int)blockIdx.x - nNormBlocks) * 256 + threadIdx.x;
    if (i < n4) out4[i] = mind4[i];
    return;
  }
  int wv = threadIdx.x >> 6;
  int lane = threadIdx.x & 63;
  int row = blockIdx.x * 4 + wv;
  const float* src;
  float* dst;
  char* bdst;
  bool isY;
  if (row < M) {
    isY = true;
    src = y + (size_t)row * DIMS; dst = y2 + row; bdst = yb + (size_t)row * DEXT;
  } else {
    int r = row - M;
    if (r >= B) return;
    isY = false;
    src = x + (size_t)r * DIMS; dst = x2 + r; bdst = xb + (size_t)r * DEXT;
  }
  const float g = isY ? -1.f : 1.f;            // store -y; x2 via scale
  float s = 0.f;
  #pragma unroll
  for (int h = 0; h < 2; ++h) {
    int c = h * 64 + lane;                     // chunk of 8 k
    const float4* fp = (const float4*)(src + c * 8);
    float4 a0 = fp[0], a1 = fp[1];
    s = fmaf(a0.x, a0.x, s); s = fmaf(a0.y, a0.y, s);
    s = fmaf(a0.z, a0.z, s); s = fmaf(a0.w, a0.w, s);
    s = fmaf(a1.x, a1.x, s); s = fmaf(a1.y, a1.y, s);
    s = fmaf(a1.z, a1.z, s); s = fmaf(a1.w, a1.w, s);
    if (PRE) {
      unsigned w = q4(g * a0.x)        | (q4(g * a0.y) << 4)  |
                   (q4(g * a0.z) << 8) | (q4(g * a0.w) << 12) |
                   (q4(g * a1.x) << 16)| (q4(g * a1.y) << 20) |
                   (q4(g * a1.z) << 24)| (q4(g * a1.w) << 28);
      *(unsigned*)(bdst + c * 4) = w;          // linear k, 4B per 8-elem chunk
    }
  }
  #pragma unroll
  for (int off = 32; off; off >>= 1) s += __shfl_xor(s, off);
  if (lane == 0) *dst = s;
  if (PRE && lane < 16) {                      // fp8 norm-digit tile @512
    if (lane == 0) {
      float u = s * 0.125f;                    // ~128; 3-digit e4m3 split
      float d1 = rintf(u * 0.0625f) * 16.f;    // ulp-16 grid
      float r1 = u - d1;
      float d2 = rintf(r1);                    // ulp-1 grid
      float d3 = rintf((r1 - d2) * 16.f) * 0.0625f;  // ulp-1/16 grid
      int w0, w1;
      if (!isY) { w0 = CVT(d1, d2, 0, 0); w0 = CVT(d3, 8.f, w0, 1);
                  w1 = CVT(8.f, 8.f, 0, 0); }
      else      { w0 = CVT(8.f, 8.f, 0, 0); w0 = CVT(8.f, d1, w0, 1);
                  w1 = CVT(d2, d3, 0, 0); }
      *(int2*)(bdst + 512) = make_int2(w0, w1);
    } else {
      *(int2*)(bdst + 512 + lane * 8) = make_int2(0, 0);
    }
  }
}

// ---------------- phase A: MX-fp4 K=128 MFMA 128x128, 4 blocks/CU ----------
// grid 1024 (rowblk=bid>>6, colchunk=bid&63); 256 thr = 4 waves 2x2, wave 64x64.
// 8 fp4 data tiles staged in PAIRS (2x16KB fits the 32KB buffer) + 1 fp8 norm
// tile -> 5 sync rounds. Per fp4 tile/wave: 8 ds_read_b128 + 16 K=128 MFMA.
template<bool PRE>
__global__ __launch_bounds__(256, 4) void knn_mx4(
    const float* __restrict__ xf, const float* __restrict__ yf,
    const char* __restrict__ xb, const char* __restrict__ yb,
    const float* __restrict__ x2, const float* __restrict__ y2,
    float* __restrict__ topk_out,           // [nch][B][8] squared dists
    const int* __restrict__ xsp, const int* __restrict__ ysp,
    int B, int M, int nch) {
  __shared__ __align__(16) char smem[32768]; // A 16KB + B 16KB; 4KB reuse at end
  const int tid = threadIdx.x;
  const int wv = tid >> 6, l = tid & 63;
  const int wr = wv >> 1, wc = wv & 1;
  const int g4 = l >> 4, l16 = l & 15;
  const int rowblk = blockIdx.x >> 6, colchunk = blockIdx.x & 63;
  const int r0 = rowblk * BM, c0 = colchunk * BN;
  const int xs = *xsp, ys = *ysp;
  const float FINF = __builtin_inff();

  f32x4 acc[4][4];
  #pragma unroll
  for (int mi = 0; mi < 4; ++mi)
    #pragma unroll
    for (int ni = 0; ni < 4; ++ni)
      acc[mi][ni] = (f32x4){0.f, 0.f, 0.f, 0.f};

  // fp4 pair-line LDS layout per tile (8KB = 64 lines x 128B):
  // line = row>>1; slot = ((q ^ (line&3))<<1) | (row&1)  -> 2-way banks (free)
  auto STAGE4 = [&](int u) {                   // stage tiles 2u, 2u+1 (A and B)
    #pragma unroll
    for (int h = 0; h < 2; ++h)
      #pragma unroll
      for (int p = 0; p < 2; ++p) {
        int line = p * 32 + (tid >> 3);
        int slot = tid & 7;
        int r = line * 2 + (slot & 1);
        int q = (slot >> 1) ^ (line & 3);      // pre-inverse-swizzled source
        gload_lds16(xb + (size_t)(r0 + r) * DEXT + (u * 2 + h) * 64 + q * 16,
                    smem + h * 8192 + p * 4096 + tid * 16);
      }
    #pragma unroll
    for (int h = 0; h < 2; ++h)
      #pragma unroll
      for (int p = 0; p < 2; ++p) {
        int line = p * 32 + (tid >> 3);
        int slot = tid & 7;
        int r = line * 2 + (slot & 1);
        int q = (slot >> 1) ^ (line & 3);
        gload_lds16(yb + (size_t)(c0 + r) * DEXT + (u * 2 + h) * 64 + q * 16,
                    smem + 16384 + h * 8192 + p * 4096 + tid * 16);
      }
  };
  auto STAGE_N = [&]() {                       // fp8 norm tile, 128B rows
    #pragma unroll
    for (int p = 0; p < 4; ++p) {
      int row = p * 32 + (tid >> 3);
      int s = (tid & 7) ^ (row & 7);
      gload_lds16(xb + (size_t)(r0 + row) * DEXT + 512 + s * 16,
                  smem + p * 4096 + tid * 16);
    }
    #pragma unroll
    for (int p = 0; p < 4; ++p) {
      int row = p * 32 + (tid >> 3);
      int s = (tid & 7) ^ (row & 7);
      gload_lds16(yb + (size_t)(c0 + row) * DEXT + 512 + s * 16,
                  smem + 16384 + p * 4096 + tid * 16);
    }
  };

  auto LDFRAG4 = [&](const char* base, int row) -> i32x8 {   // 16B fp4 frag
    int line = row >> 1;
    int slot = ((g4 ^ (line & 3)) << 1) | (row & 1);
    i32x4 v = *(const i32x4*)(base + line * 128 + slot * 16);
    i32x8 r;
    r[0] = v[0]; r[1] = v[1]; r[2] = v[2]; r[3] = v[3];
    r[4] = 0; r[5] = 0; r[6] = 0; r[7] = 0;
    return r;
  };
  auto LDFRAG8 = [&](const char* base, int row) -> i32x8 {   // 32B fp8 frag
    i32x4 lo = *(const i32x4*)(base + row * 128 + (((g4 * 2 + 0) ^ (row & 7)) * 16));
    i32x4 hi = *(const i32x4*)(base + row * 128 + (((g4 * 2 + 1) ^ (row & 7)) * 16));
    i32x8 v;
    v[0] = lo[0]; v[1] = lo[1]; v[2] = lo[2]; v[3] = lo[3];
    v[4] = hi[0]; v[5] = hi[1]; v[6] = hi[2]; v[7] = hi[3];
    return v;
  };

  auto COMPUTE4 = [&](int h) {                 // one fp4 tile (K=128)
    const char* ab = smem + h * 8192;
    const char* bb = smem + 16384 + h * 8192;
    i32x8 bf[4];
    #pragma unroll
    for (int ni = 0; ni < 4; ++ni)
      bf[ni] = LDFRAG4(bb, wc * 64 + ni * 16 + l16);
    #pragma unroll
    for (int mi = 0; mi < 4; ++mi) {
      i32x8 a = LDFRAG4(ab, wr * 64 + mi * 16 + l16);
      #pragma unroll
      for (int ni = 0; ni < 4; ++ni)           // swapped: C[ycol][xrow]
        acc[mi][ni] = __builtin_amdgcn_mfma_scale_f32_16x16x128_f8f6f4(
            bf[ni], a, acc[mi][ni], 4, 4, 0, SCL2, 0, SCL1);  // fp4; (-y)*2
    }
  };
  auto COMPUTE_N = [&]() {                     // fp8 norm tile (unit scales)
    i32x8 bf[4];
    #pragma unroll
    for (int ni = 0; ni < 4; ++ni)
      bf[ni] = LDFRAG8(smem + 16384, wc * 64 + ni * 16 + l16);
    #pragma unroll
    for (int mi = 0; mi < 4; ++mi) {
      i32x8 a = LDFRAG8(smem, wr * 64 + mi * 16 + l16);
      #pragma unroll
      for (int ni = 0; ni < 4; ++ni)
        acc[mi][ni] = __builtin_amdgcn_mfma_scale_f32_16x16x128_f8f6f4(
            bf[ni], a, acc[mi][ni], 0, 0, 0, SCL1, 0, SCL1);
    }
  };
  auto STAGE_CONV = [&](int t) {               // fallback: f32 -> fp8 in-reg
    #pragma unroll
    for (int p = 0; p < 4; ++p) {
      int row = p * 32 + (tid >> 3);
      int s = (tid & 7) ^ (row & 7);
      {
        const float* g0 = xf + (size_t)(r0 + row) * DIMS + t * 128 + s * 16;
        float4 a0 = *(const float4*)g0, a1 = *(const float4*)(g0 + 4);
        float4 a2 = *(const float4*)(g0 + 8), a3 = *(const float4*)(g0 + 12);
        int w0 = CVT(a0.x, a0.y, 0, 0); w0 = CVT(a0.z, a0.w, w0, 1);
        int w1 = CVT(a1.x, a1.y, 0, 0); w1 = CVT(a1.z, a1.w, w1, 1);
        int w2 = CVT(a2.x, a2.y, 0, 0); w2 = CVT(a2.z, a2.w, w2, 1);
        int w3 = CVT(a3.x, a3.y, 0, 0); w3 = CVT(a3.z, a3.w, w3, 1);
        *(int4*)(smem + p * 4096 + tid * 16) = make_int4(w0, w1, w2, w3);
      }
      {
        const float* g0 = yf + (size_t)(c0 + row) * DIMS + t * 128 + s * 16;
        float4 a0 = *(const float4*)g0, a1 = *(const float4*)(g0 + 4);
        float4 a2 = *(const float4*)(g0 + 8), a3 = *(const float4*)(g0 + 12);
        int w0 = CVT(a0.x, a0.y, 0, 0); w0 = CVT(a0.z, a0.w, w0, 1);
        int w1 = CVT(a1.x, a1.y, 0, 0); w1 = CVT(a1.z, a1.w, w1, 1);
        int w2 = CVT(a2.x, a2.y, 0, 0); w2 = CVT(a2.z, a2.w, w2, 1);
        int w3 = CVT(a3.x, a3.y, 0, 0); w3 = CVT(a3.z, a3.w, w3, 1);
        *(int4*)(smem + 16384 + p * 4096 + tid * 16) = make_int4(w0, w1, w2, w3);
      }
    }
  };

  if (PRE) {
    #pragma unroll 1
    for (int u = 0; u < 4; ++u) {              // 4 rounds x 2 fp4 tiles
      __syncthreads();                         // prev round's readers done
      STAGE4(u);
      __syncthreads();                         // pair staged (vmcnt drained)
      COMPUTE4(0);
      COMPUTE4(1);
    }
    __syncthreads();
    STAGE_N();                                 // norm tile round (fp8)
    __syncthreads();
    COMPUTE_N();
  } else {
    #pragma unroll 1
    for (int t = 0; t < DIMS / 128; ++t) {
      __syncthreads();
      STAGE_CONV(t);
      __syncthreads();
      // fp8 tile, unit scales: acc accumulates x.y (note: NOT -2x.y)
      i32x8 bf[4];
      #pragma unroll
      for (int ni = 0; ni < 4; ++ni)
        bf[ni] = LDFRAG8(smem + 16384, wc * 64 + ni * 16 + l16);
      #pragma unroll
      for (int mi = 0; mi < 4; ++mi) {
        i32x8 a = LDFRAG8(smem, wr * 64 + mi * 16 + l16);
        #pragma unroll
        for (int ni = 0; ni < 4; ++ni)
          acc[mi][ni] = __builtin_amdgcn_mfma_scale_f32_16x16x128_f8f6f4(
              bf[ni], a, acc[mi][ni], 0, 0, 0, SCL1, 0, SCL1);
      }
    }
  }

  // ---- epilogue: per-lane in-register top-8 (r11/r12/r13-verified) --------
  const int cb2 = c0 + wc * 64 + g4 * 4;
  float y2v[16];
  if (!PRE) {
    #pragma unroll
    for (int ni = 0; ni < 4; ++ni)
      #pragma unroll
      for (int j = 0; j < 4; ++j)
        y2v[ni * 4 + j] = y2[cb2 + ni * 16 + j];
  }

  float t8[4][8];
  #pragma unroll
  for (int mi = 0; mi < 4; ++mi) {
    const int gr = r0 + wr * 64 + mi * 16 + l16;
    const int dmi = xs + gr - ys - cb2;        // equals ni*16+j iff self-pair
    const float xv = PRE ? 0.f : x2[gr];
    float a[8], b[8];
    #pragma unroll
    for (int ni = 0; ni < 2; ++ni)
      #pragma unroll
      for (int j = 0; j < 4; ++j) {
        float sq = PRE ? fmaxf(acc[mi][ni][j], 0.f)
                       : fmaxf(xv + y2v[ni * 4 + j] - 2.f * acc[mi][ni][j], 0.f);
        if (dmi == ni * 16 + j) sq = FINF;
        a[ni * 4 + j] = sq;
      }
    #pragma unroll
    for (int ni = 2; ni < 4; ++ni)
      #pragma unroll
      for (int j = 0; j < 4; ++j) {
        float sq = PRE ? fmaxf(acc[mi][ni][j], 0.f)
                       : fmaxf(xv + y2v[ni * 4 + j] - 2.f * acc[mi][ni][j], 0.f);
        if (dmi == ni * 16 + j) sq = FINF;
        b[(ni - 2) * 4 + j] = sq;
      }
    sort8(a); sort8(b); merge8(a, b);          // top8 of lane's 16, ascending
    #pragma unroll
    for (int k = 0; k < 8; ++k) b[k] = __shfl_xor(a[k], 16);
    merge8(a, b);
    #pragma unroll
    for (int k = 0; k < 8; ++k) b[k] = __shfl_xor(a[k], 32);
    merge8(a, b);                              // all 4 g4 groups merged
    #pragma unroll
    for (int k = 0; k < 8; ++k) t8[mi][k] = a[k];
  }

  float* xbuf = (float*)smem;                  // 4KB hop to merge wc strips
  __syncthreads();
  if (wc == 1 && g4 == 0) {
    #pragma unroll
    for (int mi = 0; mi < 4; ++mi) {
      float* p = xbuf + ((wr * 4 + mi) * 16 + l16) * 8;
      *(f32x4*)p       = (f32x4){t8[mi][0], t8[mi][1], t8[mi][2], t8[mi][3]};
      *((f32x4*)p + 1) = (f32x4){t8[mi][4], t8[mi][5], t8[mi][6], t8[mi][7]};
    }
  }
  __syncthreads();
  if (wc == 0 && g4 == 0) {
    #pragma unroll
    for (int mi = 0; mi < 4; ++mi) {
      const float* p = xbuf + ((wr * 4 + mi) * 16 + l16) * 8;
      float b[8];
      #pragma unroll
      for (int k = 0; k < 8; ++k) b[k] = p[k];
      merge8(t8[mi], b);
      int gr = r0 + wr * 64 + mi * 16 + l16;
      float* o = topk_out + ((size_t)colchunk * B + gr) * 8;
      *(f32x4*)o       = (f32x4){t8[mi][0], t8[mi][1], t8[mi][2], t8[mi][3]};
      *((f32x4*)o + 1) = (f32x4){t8[mi][4], t8[mi][5], t8[mi][6], t8[mi][7]};
    }
  }
}

// ---------------- phase B: wave-per-row merge of nch sorted lists ----------
__global__ void knn_phaseB(const float* __restrict__ topk,
                           const float* __restrict__ mind_in,
                           float* __restrict__ out,
                           const int* __restrict__ xsp, int B, int nch) {
  int w = threadIdx.x >> 6, lane = threadIdx.x & 63;
  int r = blockIdx.x * 4 + w;
  if (r >= B) return;
  int x_start = *xsp;
  const float* bp = topk + ((size_t)lane * B + r) * 8;   // chunk = lane (nch=64)
  float t8[8];
  f32x4 v0 = *(const f32x4*)bp;
  f32x4 v1 = *(const f32x4*)(bp + 4);
  t8[0]=v0[0]; t8[1]=v0[1]; t8[2]=v0[2]; t8[3]=v0[3];
  t8[4]=v1[0]; t8[5]=v1[1]; t8[6]=v1[2]; t8[7]=v1[3];
  #pragma unroll
  for (int off = 32; off >= 1; off >>= 1) {              // butterfly merge
    float b[8];
    #pragma unroll
    for (int k = 0; k < 8; ++k) b[k] = __shfl_xor(t8[k], off);
    merge8(t8, b);
  }
  if (lane == 0) {
    float lst[8];
    #pragma unroll
    for (int k = 0; k < 8; ++k) lst[k] = sqrtf(t8[k]);   // squared -> distance
    float cur[8];
    const float* cp = mind_in + (size_t)(x_start + r) * KNN_K;
    #pragma unroll
    for (int k = 0; k < 8; ++k) cur[k] = cp[k];
    sort8(cur);
    merge8(lst, cur);
    #pragma unroll
    for (int k = 0; k < 8; ++k) out[(size_t)(x_start + r) * KNN_K + k] = lst[k];
  }
}

extern "C" void kernel_launch(void* const* d_in, const int* in_sizes, int n_in,
                              void* d_out, int out_size, void* d_ws, size_t ws_size,
                              hipStream_t stream) {
  const float* x = (const float*)d_in[0];
  const float* y = (const float*)d_in[1];
  const float* mind = (const float*)d_in[2];
  const int* xsp = (const int*)d_in[3];
  const int* ysp = (const int*)d_in[4];
  float* out = (float*)d_out;

  const int B = in_sizes[0] / DIMS;       // 2048
  const int M = in_sizes[1] / DIMS;       // 8192
  const int nch = M / BN;                 // 64

  float* y2 = (float*)d_ws;               // [M]
  float* x2 = y2 + M;                     // [B]
  float* topk = x2 + B;                   // [nch][B][8]
  size_t base = ((size_t)(M + B) + (size_t)B * nch * 8) * 4;
  base = (base + 255) & ~(size_t)255;
  char* xbw = (char*)d_ws + base;
  char* ybw = xbw + (size_t)B * DEXT;
  size_t need = base + ((size_t)B + (size_t)M) * DEXT;
  bool pre = ws_size >= need;

  int nNorm = (B + M + 3) / 4;
  int n4 = out_size / 4;
  int nCopy = (n4 + 255) / 256;
  if (pre)
    prep_kernel<true><<<nNorm + nCopy, 256, 0, stream>>>(
        x, y, x2, y2, xbw, ybw, (const float4*)mind, (float4*)out, n4, B, M, nNorm);
  else
    prep_kernel<false><<<nNorm + nCopy, 256, 0, stream>>>(
        x, y, x2, y2, xbw, ybw, (const float4*)mind, (float4*)out, n4, B, M, nNorm);

  int nBlocks = (B / BM) * nch;           // 16 x 64 = 1024 (4 blocks/CU)
  if (pre)
    knn_mx4<true><<<nBlocks, 256, 0, stream>>>(x, y, xbw, ybw, x2, y2, topk, xsp, ysp, B, M, nch);
  else
    knn_mx4<false><<<nBlocks, 256, 0, stream>>>(x, y, xbw, ybw, x2, y2, topk, xsp, ysp, B, M, nch);

  knn_phaseB<<<(B + 3) / 4, 256, 0, stream>>>(topk, mind, out, xsp, B, nch);
}

// Round 15
// 40.629 us; speedup vs baseline: 3.2927x; 1.0715x over previous
//
#include <hip/hip_runtime.h>

#define DIMS 1024
#define DEXT 512         // bytes/row: 512 fp4 data (norms handled in epilogue)
#define KNN_K 8
#define BM 128
#define BN 128

typedef float f32x4 __attribute__((ext_vector_type(4)));
typedef int i32x4 __attribute__((ext_vector_type(4)));
typedef int i32x8 __attribute__((ext_vector_type(8)));

#define CVT(a, b, old, w) __builtin_amdgcn_cvt_pk_fp8_f32((a), (b), (old), (w))
#define SCL1 0x7f7f7f7f  // E8M0 127 -> x1
#define SCL2 0x80808080  // E8M0 128 -> x2 (folds the -2 into -y's scale)

// compare-exchange (ascending)
__device__ __forceinline__ void ce(float& a, float& b) {
  float lo = fminf(a, b), hi = fmaxf(a, b); a = lo; b = hi;
}
// Batcher odd-even merge sort, 8 elements ascending (19 CE, branch-free)
__device__ __forceinline__ void sort8(float (&v)[8]) {
  ce(v[0],v[1]); ce(v[2],v[3]); ce(v[4],v[5]); ce(v[6],v[7]);
  ce(v[0],v[2]); ce(v[1],v[3]); ce(v[4],v[6]); ce(v[5],v[7]);
  ce(v[1],v[2]); ce(v[5],v[6]);
  ce(v[0],v[4]); ce(v[1],v[5]); ce(v[2],v[6]); ce(v[3],v[7]);
  ce(v[2],v[4]); ce(v[3],v[5]);
  ce(v[1],v[2]); ce(v[3],v[4]); ce(v[5],v[6]);
}
// a,b ascending sorted-8 -> a = smallest 8 of union, ascending
__device__ __forceinline__ void merge8(float (&a)[8], const float (&b)[8]) {
  float u[8];
  #pragma unroll
  for (int k = 0; k < 8; ++k) u[k] = fminf(a[k], b[7 - k]);  // bitonic
  ce(u[0],u[4]); ce(u[1],u[5]); ce(u[2],u[6]); ce(u[3],u[7]);
  ce(u[0],u[2]); ce(u[1],u[3]); ce(u[4],u[6]); ce(u[5],u[7]);
  ce(u[0],u[1]); ce(u[2],u[3]); ce(u[4],u[5]); ce(u[6],u[7]);
  #pragma unroll
  for (int k = 0; k < 8; ++k) a[k] = u[k];
}

__device__ __forceinline__ void gload_lds16(const void* g, void* l) {
  __builtin_amdgcn_global_load_lds(
      (const __attribute__((address_space(1))) void*)g,
      (__attribute__((address_space(3))) void*)l, 16, 0, 0);
}

// e2m1 quantize (round-to-nearest): {0,.5,1,1.5,2,3,4,6} + sign
__device__ __forceinline__ unsigned q4(float v) {
  float a = fabsf(v);
  unsigned code = (a >= 0.25f) + (a >= 0.75f) + (a >= 1.25f) + (a >= 1.75f)
                + (a >= 2.5f) + (a >= 3.5f) + (a >= 5.f);
  return (v < 0.f ? 8u : 0u) | code;
}

// ---- prep: norms + fp4 pack (x, -y) + min_dists->out copy ------------------
// Data MFMA uses scale 2 on the (-y) operand => acc = -2 x.y; epilogue adds
// exact f32 x2[r] + y2[c] => squared distance.
template<bool PRE>
__global__ void prep_kernel(const float* __restrict__ x, const float* __restrict__ y,
                            float* __restrict__ x2, float* __restrict__ y2,
                            char* __restrict__ xb, char* __restrict__ yb,
                            const float4* __restrict__ mind4, float4* __restrict__ out4,
                            int n4, int B, int M, int nNormBlocks) {
  if ((int)blockIdx.x >= nNormBlocks) {        // tail blocks: full-buffer copy
    int i = ((int)blockIdx.x - nNormBlocks) * 256 + threadIdx.x;
    if (i < n4) out4[i] = mind4[i];
    return;
  }
  int wv = threadIdx.x >> 6;
  int lane = threadIdx.x & 63;
  int row = blockIdx.x * 4 + wv;
  const float* src;
  float* dst;
  char* bdst;
  bool isY;
  if (row < M) {
    isY = true;
    src = y + (size_t)row * DIMS; dst = y2 + row; bdst = yb + (size_t)row * DEXT;
  } else {
    int r = row - M;
    if (r >= B) return;
    isY = false;
    src = x + (size_t)r * DIMS; dst = x2 + r; bdst = xb + (size_t)r * DEXT;
  }
  const float g = isY ? -1.f : 1.f;            // store -y; x(-2) via MX scale
  float s = 0.f;
  #pragma unroll
  for (int h = 0; h < 2; ++h) {
    int c = h * 64 + lane;                     // chunk of 8 k
    const float4* fp = (const float4*)(src + c * 8);
    float4 a0 = fp[0], a1 = fp[1];
    s = fmaf(a0.x, a0.x, s); s = fmaf(a0.y, a0.y, s);
    s = fmaf(a0.z, a0.z, s); s = fmaf(a0.w, a0.w, s);
    s = fmaf(a1.x, a1.x, s); s = fmaf(a1.y, a1.y, s);
    s = fmaf(a1.z, a1.z, s); s = fmaf(a1.w, a1.w, s);
    if (PRE) {
      unsigned w = q4(g * a0.x)        | (q4(g * a0.y) << 4)  |
                   (q4(g * a0.z) << 8) | (q4(g * a0.w) << 12) |
                   (q4(g * a1.x) << 16)| (q4(g * a1.y) << 20) |
                   (q4(g * a1.z) << 24)| (q4(g * a1.w) << 28);
      *(unsigned*)(bdst + c * 4) = w;          // linear k, 4B per 8-elem chunk
    }
  }
  #pragma unroll
  for (int off = 32; off; off >>= 1) s += __shfl_xor(s, off);
  if (lane == 0) *dst = s;
}

// ---------------- phase A: MX-fp4 K=128 MFMA 128x128, dbuf, 4 blocks/CU ----
// grid 1024 (rowblk=bid>>6, colchunk=bid&63); 256 thr = 4 waves 2x2, wave 64x64.
// 8 fp4 tiles (16KB each: A 8KB + B 8KB) double-buffered in 32KB LDS with
// counted vmcnt (stage t+1 in flight while computing t; never drain to 0
// mid-loop). Epilogue adds exact f32 norms (x2/y2 are L1-resident).
template<bool PRE>
__global__ __launch_bounds__(256, 4) void knn_mx4(
    const float* __restrict__ xf, const float* __restrict__ yf,
    const char* __restrict__ xb, const char* __restrict__ yb,
    const float* __restrict__ x2, const float* __restrict__ y2,
    float* __restrict__ topk_out,           // [nch][B][8] squared dists
    const int* __restrict__ xsp, const int* __restrict__ ysp,
    int B, int M, int nch) {
  __shared__ __align__(16) char smem[32768]; // 2 x (A 8KB + B 8KB); 4KB reuse
  const int tid = threadIdx.x;
  const int wv = tid >> 6, l = tid & 63;
  const int wr = wv >> 1, wc = wv & 1;
  const int g4 = l >> 4, l16 = l & 15;
  const int rowblk = blockIdx.x >> 6, colchunk = blockIdx.x & 63;
  const int r0 = rowblk * BM, c0 = colchunk * BN;
  const int xs = *xsp, ys = *ysp;
  const float FINF = __builtin_inff();

  f32x4 acc[4][4];
  #pragma unroll
  for (int mi = 0; mi < 4; ++mi)
    #pragma unroll
    for (int ni = 0; ni < 4; ++ni)
      acc[mi][ni] = (f32x4){0.f, 0.f, 0.f, 0.f};

  // fp4 pair-line LDS layout per tile (8KB = 64 lines x 128B):
  // line = row>>1; slot = ((q ^ (line&3))<<1) | (row&1)  -> 2-way banks (free)
  auto STAGE1 = [&](char* base, int t) {       // one tile pair: 4 gload/thread
    #pragma unroll
    for (int p = 0; p < 2; ++p) {
      int line = p * 32 + (tid >> 3);
      int slot = tid & 7;
      int r = line * 2 + (slot & 1);
      int q = (slot >> 1) ^ (line & 3);        // pre-inverse-swizzled source
      gload_lds16(xb + (size_t)(r0 + r) * DEXT + t * 64 + q * 16,
                  base + p * 4096 + tid * 16);
    }
    #pragma unroll
    for (int p = 0; p < 2; ++p) {
      int line = p * 32 + (tid >> 3);
      int slot = tid & 7;
      int r = line * 2 + (slot & 1);
      int q = (slot >> 1) ^ (line & 3);
      gload_lds16(yb + (size_t)(c0 + r) * DEXT + t * 64 + q * 16,
                  base + 8192 + p * 4096 + tid * 16);
    }
  };

  auto LDFRAG4 = [&](const char* base, int row) -> i32x8 {   // 16B fp4 frag
    int line = row >> 1;
    int slot = ((g4 ^ (line & 3)) << 1) | (row & 1);
    i32x4 v = *(const i32x4*)(base + line * 128 + slot * 16);
    i32x8 r;
    r[0] = v[0]; r[1] = v[1]; r[2] = v[2]; r[3] = v[3];
    r[4] = 0; r[5] = 0; r[6] = 0; r[7] = 0;
    return r;
  };
  auto LDFRAG8 = [&](const char* base, int row) -> i32x8 {   // 32B fp8 frag
    i32x4 lo = *(const i32x4*)(base + row * 128 + (((g4 * 2 + 0) ^ (row & 7)) * 16));
    i32x4 hi = *(const i32x4*)(base + row * 128 + (((g4 * 2 + 1) ^ (row & 7)) * 16));
    i32x8 v;
    v[0] = lo[0]; v[1] = lo[1]; v[2] = lo[2]; v[3] = lo[3];
    v[4] = hi[0]; v[5] = hi[1]; v[6] = hi[2]; v[7] = hi[3];
    return v;
  };

  auto COMPUTE1 = [&](const char* base) {      // one fp4 tile (K=128)
    const char* bb = base + 8192;
    i32x8 bf[4];
    #pragma unroll
    for (int ni = 0; ni < 4; ++ni)
      bf[ni] = LDFRAG4(bb, wc * 64 + ni * 16 + l16);
    #pragma unroll
    for (int mi = 0; mi < 4; ++mi) {
      i32x8 a = LDFRAG4(base, wr * 64 + mi * 16 + l16);
      #pragma unroll
      for (int ni = 0; ni < 4; ++ni)           // swapped: C[ycol][xrow]
        acc[mi][ni] = __builtin_amdgcn_mfma_scale_f32_16x16x128_f8f6f4(
            bf[ni], a, acc[mi][ni], 4, 4, 0, SCL2, 0, SCL1);  // fp4; (-y)*2
    }
  };
  auto STAGE_CONV = [&](int t) {               // fallback: f32 -> fp8 in-reg
    #pragma unroll
    for (int p = 0; p < 4; ++p) {
      int row = p * 32 + (tid >> 3);
      int s = (tid & 7) ^ (row & 7);
      {
        const float* g0 = xf + (size_t)(r0 + row) * DIMS + t * 128 + s * 16;
        float4 a0 = *(const float4*)g0, a1 = *(const float4*)(g0 + 4);
        float4 a2 = *(const float4*)(g0 + 8), a3 = *(const float4*)(g0 + 12);
        int w0 = CVT(a0.x, a0.y, 0, 0); w0 = CVT(a0.z, a0.w, w0, 1);
        int w1 = CVT(a1.x, a1.y, 0, 0); w1 = CVT(a1.z, a1.w, w1, 1);
        int w2 = CVT(a2.x, a2.y, 0, 0); w2 = CVT(a2.z, a2.w, w2, 1);
        int w3 = CVT(a3.x, a3.y, 0, 0); w3 = CVT(a3.z, a3.w, w3, 1);
        *(int4*)(smem + p * 4096 + tid * 16) = make_int4(w0, w1, w2, w3);
      }
      {
        const float* g0 = yf + (size_t)(c0 + row) * DIMS + t * 128 + s * 16;
        float4 a0 = *(const float4*)g0, a1 = *(const float4*)(g0 + 4);
        float4 a2 = *(const float4*)(g0 + 8), a3 = *(const float4*)(g0 + 12);
        int w0 = CVT(a0.x, a0.y, 0, 0); w0 = CVT(a0.z, a0.w, w0, 1);
        int w1 = CVT(a1.x, a1.y, 0, 0); w1 = CVT(a1.z, a1.w, w1, 1);
        int w2 = CVT(a2.x, a2.y, 0, 0); w2 = CVT(a2.z, a2.w, w2, 1);
        int w3 = CVT(a3.x, a3.y, 0, 0); w3 = CVT(a3.z, a3.w, w3, 1);
        *(int4*)(smem + 16384 + p * 4096 + tid * 16) = make_int4(w0, w1, w2, w3);
      }
    }
  };

  if (PRE) {
    STAGE1(smem, 0);                           // prologue: tile 0 in flight
    #pragma unroll 1
    for (int t = 0; t < 8; ++t) {
      char* cb = smem + (t & 1) * 16384;
      char* nb = smem + ((t + 1) & 1) * 16384;
      if (t + 1 < 8) {
        STAGE1(nb, t + 1);                     // 4 loads -> other buffer (its
                                               //  readers finished at t-1 bar)
        asm volatile("s_waitcnt vmcnt(4)" ::: "memory");  // tile t landed only
      } else {
        asm volatile("s_waitcnt vmcnt(0)" ::: "memory");
      }
      asm volatile("s_barrier" ::: "memory");  // tile t visible to all waves
      COMPUTE1(cb);
      asm volatile("s_barrier" ::: "memory");  // all waves done reading tile t
    }
  } else {
    #pragma unroll 1
    for (int t = 0; t < DIMS / 128; ++t) {
      __syncthreads();
      STAGE_CONV(t);
      __syncthreads();
      // fp8 tile, unit scales: acc accumulates x.y (note: NOT -2x.y)
      i32x8 bf[4];
      #pragma unroll
      for (int ni = 0; ni < 4; ++ni)
        bf[ni] = LDFRAG8(smem + 16384, wc * 64 + ni * 16 + l16);
      #pragma unroll
      for (int mi = 0; mi < 4; ++mi) {
        i32x8 a = LDFRAG8(smem, wr * 64 + mi * 16 + l16);
        #pragma unroll
        for (int ni = 0; ni < 4; ++ni)
          acc[mi][ni] = __builtin_amdgcn_mfma_scale_f32_16x16x128_f8f6f4(
              bf[ni], a, acc[mi][ni], 0, 0, 0, SCL1, 0, SCL1);
      }
    }
  }

  // ---- epilogue: per-lane in-register top-8; exact f32 norms added here ---
  const int cb2 = c0 + wc * 64 + g4 * 4;
  float y2v[16];
  #pragma unroll
  for (int ni = 0; ni < 4; ++ni)
    #pragma unroll
    for (int j = 0; j < 4; ++j)
      y2v[ni * 4 + j] = y2[cb2 + ni * 16 + j];

  float t8[4][8];
  #pragma unroll
  for (int mi = 0; mi < 4; ++mi) {
    const int gr = r0 + wr * 64 + mi * 16 + l16;
    const int dmi = xs + gr - ys - cb2;        // equals ni*16+j iff self-pair
    const float xv = x2[gr];
    float a[8], b[8];
    #pragma unroll
    for (int ni = 0; ni < 2; ++ni)
      #pragma unroll
      for (int j = 0; j < 4; ++j) {
        float sq = PRE ? fmaxf(xv + y2v[ni * 4 + j] + acc[mi][ni][j], 0.f)
                       : fmaxf(xv + y2v[ni * 4 + j] - 2.f * acc[mi][ni][j], 0.f);
        if (dmi == ni * 16 + j) sq = FINF;
        a[ni * 4 + j] = sq;
      }
    #pragma unroll
    for (int ni = 2; ni < 4; ++ni)
      #pragma unroll
      for (int j = 0; j < 4; ++j) {
        float sq = PRE ? fmaxf(xv + y2v[ni * 4 + j] + acc[mi][ni][j], 0.f)
                       : fmaxf(xv + y2v[ni * 4 + j] - 2.f * acc[mi][ni][j], 0.f);
        if (dmi == ni * 16 + j) sq = FINF;
        b[(ni - 2) * 4 + j] = sq;
      }
    sort8(a); sort8(b); merge8(a, b);          // top8 of lane's 16, ascending
    #pragma unroll
    for (int k = 0; k < 8; ++k) b[k] = __shfl_xor(a[k], 16);
    merge8(a, b);
    #pragma unroll
    for (int k = 0; k < 8; ++k) b[k] = __shfl_xor(a[k], 32);
    merge8(a, b);                              // all 4 g4 groups merged
    #pragma unroll
    for (int k = 0; k < 8; ++k) t8[mi][k] = a[k];
  }

  float* xbuf = (float*)smem;                  // 4KB hop to merge wc strips
  __syncthreads();
  if (wc == 1 && g4 == 0) {
    #pragma unroll
    for (int mi = 0; mi < 4; ++mi) {
      float* p = xbuf + ((wr * 4 + mi) * 16 + l16) * 8;
      *(f32x4*)p       = (f32x4){t8[mi][0], t8[mi][1], t8[mi][2], t8[mi][3]};
      *((f32x4*)p + 1) = (f32x4){t8[mi][4], t8[mi][5], t8[mi][6], t8[mi][7]};
    }
  }
  __syncthreads();
  if (wc == 0 && g4 == 0) {
    #pragma unroll
    for (int mi = 0; mi < 4; ++mi) {
      const float* p = xbuf + ((wr * 4 + mi) * 16 + l16) * 8;
      float b[8];
      #pragma unroll
      for (int k = 0; k < 8; ++k) b[k] = p[k];
      merge8(t8[mi], b);
      int gr = r0 + wr * 64 + mi * 16 + l16;
      float* o = topk_out + ((size_t)colchunk * B + gr) * 8;
      *(f32x4*)o       = (f32x4){t8[mi][0], t8[mi][1], t8[mi][2], t8[mi][3]};
      *((f32x4*)o + 1) = (f32x4){t8[mi][4], t8[mi][5], t8[mi][6], t8[mi][7]};
    }
  }
}

// ---------------- phase B: wave-per-row merge of nch sorted lists ----------
__global__ void knn_phaseB(const float* __restrict__ topk,
                           const float* __restrict__ mind_in,
                           float* __restrict__ out,
                           const int* __restrict__ xsp, int B, int nch) {
  int w = threadIdx.x >> 6, lane = threadIdx.x & 63;
  int r = blockIdx.x * 4 + w;
  if (r >= B) return;
  int x_start = *xsp;
  const float* bp = topk + ((size_t)lane * B + r) * 8;   // chunk = lane (nch=64)
  float t8[8];
  f32x4 v0 = *(const f32x4*)bp;
  f32x4 v1 = *(const f32x4*)(bp + 4);
  t8[0]=v0[0]; t8[1]=v0[1]; t8[2]=v0[2]; t8[3]=v0[3];
  t8[4]=v1[0]; t8[5]=v1[1]; t8[6]=v1[2]; t8[7]=v1[3];
  #pragma unroll
  for (int off = 32; off >= 1; off >>= 1) {              // butterfly merge
    float b[8];
    #pragma unroll
    for (int k = 0; k < 8; ++k) b[k] = __shfl_xor(t8[k], off);
    merge8(t8, b);
  }
  if (lane == 0) {
    float lst[8];
    #pragma unroll
    for (int k = 0; k < 8; ++k) lst[k] = sqrtf(t8[k]);   // squared -> distance
    float cur[8];
    const float* cp = mind_in + (size_t)(x_start + r) * KNN_K;
    #pragma unroll
    for (int k = 0; k < 8; ++k) cur[k] = cp[k];
    sort8(cur);
    merge8(lst, cur);
    #pragma unroll
    for (int k = 0; k < 8; ++k) out[(size_t)(x_start + r) * KNN_K + k] = lst[k];
  }
}

extern "C" void kernel_launch(void* const* d_in, const int* in_sizes, int n_in,
                              void* d_out, int out_size, void* d_ws, size_t ws_size,
                              hipStream_t stream) {
  const float* x = (const float*)d_in[0];
  const float* y = (const float*)d_in[1];
  const float* mind = (const float*)d_in[2];
  const int* xsp = (const int*)d_in[3];
  const int* ysp = (const int*)d_in[4];
  float* out = (float*)d_out;

  const int B = in_sizes[0] / DIMS;       // 2048
  const int M = in_sizes[1] / DIMS;       // 8192
  const int nch = M / BN;                 // 64

  float* y2 = (float*)d_ws;               // [M]
  float* x2 = y2 + M;                     // [B]
  float* topk = x2 + B;                   // [nch][B][8]
  size_t base = ((size_t)(M + B) + (size_t)B * nch * 8) * 4;
  base = (base + 255) & ~(size_t)255;
  char* xbw = (char*)d_ws + base;
  char* ybw = xbw + (size_t)B * DEXT;
  size_t need = base + ((size_t)B + (size_t)M) * DEXT;
  bool pre = ws_size >= need;

  int nNorm = (B + M + 3) / 4;
  int n4 = out_size / 4;
  int nCopy = (n4 + 255) / 256;
  if (pre)
    prep_kernel<true><<<nNorm + nCopy, 256, 0, stream>>>(
        x, y, x2, y2, xbw, ybw, (const float4*)mind, (float4*)out, n4, B, M, nNorm);
  else
    prep_kernel<false><<<nNorm + nCopy, 256, 0, stream>>>(
        x, y, x2, y2, xbw, ybw, (const float4*)mind, (float4*)out, n4, B, M, nNorm);

  int nBlocks = (B / BM) * nch;           // 16 x 64 = 1024 (4 blocks/CU)
  if (pre)
    knn_mx4<true><<<nBlocks, 256, 0, stream>>>(x, y, xbw, ybw, x2, y2, topk, xsp, ysp, B, M, nch);
  else
    knn_mx4<false><<<nBlocks, 256, 0, stream>>>(x, y, xbw, ybw, x2, y2, topk, xsp, ysp, B, M, nch);

  knn_phaseB<<<(B + 3) / 4, 256, 0, stream>>>(topk, mind, out, xsp, B, nch);
}